// Round 8
// baseline (371.883 us; speedup 1.0000x reference)
//
#include <hip/hip_runtime.h>
#include <hip/hip_bf16.h>
#include <hip/hip_fp16.h>
#include <math.h>

#define NFEAT 128
#define NHID  64
#define SCAN_B 1024
#define ATH996 3.106303f   // artanh(0.996)

typedef __attribute__((ext_vector_type(8))) short short8;
typedef __attribute__((ext_vector_type(4))) float floatx4;
typedef unsigned short ushort_t;

__device__ __forceinline__ float wave_sum(float v) {
#pragma unroll
    for (int m = 1; m < 64; m <<= 1) v += __shfl_xor(v, m, 64);
    return v;
}

__device__ __forceinline__ float fast_tanh(float x) {
    float e = __expf(2.f * x);
    return 1.f - 2.f / (e + 1.f);
}

__device__ __forceinline__ float artanh_clip(float v) {
    const float lim = 0.99999988f;  // float(1 - 1e-7)
    v = fminf(fmaxf(v, -lim), lim);
    return 0.5f * __logf((1.f + v) / (1.f - v));
}

__device__ __forceinline__ unsigned pack2(float a, float b) {
    __hip_bfloat16 x = __float2bfloat16(a), y = __float2bfloat16(b);
    ushort_t ux = *(ushort_t*)&x, uy = *(ushort_t*)&y;
    return (unsigned)ux | ((unsigned)uy << 16);
}

__device__ __forceinline__ float bf2f(ushort_t u) {
    return __uint_as_float(((unsigned)u) << 16);
}
__device__ __forceinline__ ushort_t f2bf(float f) {
    __hip_bfloat16 h = __float2bfloat16(f);
    return *(ushort_t*)&h;
}

// packed edge: bits[31:15] = src (17b), bits[14:0] = fp16(adj) sans sign
__device__ __forceinline__ float pe_adj(unsigned p) {
    return __half2float(__ushort_as_half((ushort_t)(p & 0x7fffu)));
}

// ---- CSR build (XCD-sharded histogram) --------------------------------------

// shard = blockIdx&7 ~ XCD; cnt8 is shard-major so each shard's 400KB region
// is atomically updated (mostly) from one XCD's L2 -> no cross-XCD line bounce
__global__ __launch_bounds__(256) void k_rank(const int* __restrict__ dst,
        int* __restrict__ cnt8, int* __restrict__ lr, int e, int n) {
    int i = blockIdx.x * 256 + threadIdx.x;
    int s = blockIdx.x & 7;
    if (i < e) lr[i] = atomicAdd(&cnt8[s * n + dst[i]], 1);
}

// scan over M = 8N logical cells in (node-major, shard-minor) order;
// loads are a transposed gather from the shard-major cnt8
__global__ __launch_bounds__(256) void k_scan1(const int* __restrict__ cnt8,
        int* __restrict__ off, int* __restrict__ bsums, int m, int n) {
    __shared__ int s[256];
    int tid = threadIdx.x;
    int base = blockIdx.x * SCAN_B + tid * 4;
    int c0 = 0, c1 = 0, c2 = 0, c3 = 0;
    if (base + 0 < m) c0 = cnt8[((base + 0) & 7) * n + ((base + 0) >> 3)];
    if (base + 1 < m) c1 = cnt8[((base + 1) & 7) * n + ((base + 1) >> 3)];
    if (base + 2 < m) c2 = cnt8[((base + 2) & 7) * n + ((base + 2) >> 3)];
    if (base + 3 < m) c3 = cnt8[((base + 3) & 7) * n + ((base + 3) >> 3)];
    int tsum = c0 + c1 + c2 + c3;
    s[tid] = tsum; __syncthreads();
    for (int o = 1; o < 256; o <<= 1) {
        int v = (tid >= o) ? s[tid - o] : 0;
        __syncthreads();
        s[tid] += v;
        __syncthreads();
    }
    int excl = s[tid] - tsum;
    if (base + 0 < m) off[base + 0] = excl;
    if (base + 1 < m) off[base + 1] = excl + c0;
    if (base + 2 < m) off[base + 2] = excl + c0 + c1;
    if (base + 3 < m) off[base + 3] = excl + c0 + c1 + c2;
    if (tid == 255) bsums[blockIdx.x] = s[255];
}

__global__ __launch_bounds__(256) void k_scan2(int* __restrict__ bsums, int nb,
                                               int* __restrict__ off, int ntot) {
    __shared__ int s[256];
    int tid = threadIdx.x;
    int base = tid * 4;
    int c0 = 0, c1 = 0, c2 = 0, c3 = 0;
    if (base + 0 < nb) c0 = bsums[base + 0];
    if (base + 1 < nb) c1 = bsums[base + 1];
    if (base + 2 < nb) c2 = bsums[base + 2];
    if (base + 3 < nb) c3 = bsums[base + 3];
    int tsum = c0 + c1 + c2 + c3;
    s[tid] = tsum; __syncthreads();
    for (int o = 1; o < 256; o <<= 1) {
        int v = (tid >= o) ? s[tid - o] : 0;
        __syncthreads();
        s[tid] += v;
        __syncthreads();
    }
    int excl = s[tid] - tsum;
    if (base + 0 < nb) bsums[base + 0] = excl;
    if (base + 1 < nb) bsums[base + 1] = excl + c0;
    if (base + 2 < nb) bsums[base + 2] = excl + c0 + c1;
    if (base + 3 < nb) bsums[base + 3] = excl + c0 + c1 + c2;
    if (tid == 255) off[ntot] = s[255];
}

__global__ __launch_bounds__(256) void k_scan3(int* __restrict__ off,
        const int* __restrict__ bsums, int m) {
    int i = blockIdx.x * 256 + threadIdx.x;
    if (i < m) off[i] += bsums[i >> 10];
}

// fused build+gather: scatter packed (src|fp16 adj) directly to final slot
__global__ __launch_bounds__(256) void k_build(const int* __restrict__ dst,
        const int* __restrict__ src, const float* __restrict__ adj,
        const int* __restrict__ off8, const int* __restrict__ lr,
        unsigned* __restrict__ pe, int e) {
    int i = blockIdx.x * 256 + threadIdx.x;
    int s = blockIdx.x & 7;   // must match k_rank's shard for this edge
    if (i < e) {
        int pos = off8[((size_t)dst[i] << 3) | s] + lr[i];
        unsigned ab = (unsigned)__half_as_ushort(__float2half(adj[i])) & 0x7fffu;
        pe[pos] = ((unsigned)src[i] << 15) | ab;
    }
}

// ---- one-shot prep: all weight packs + hyperbolic biases --------------------
__global__ __launch_bounds__(256) void k_prep(
        const float* __restrict__ W1, const float* __restrict__ W2,
        const float* __restrict__ W3, const float* __restrict__ W4,
        const float* __restrict__ W5, const float* __restrict__ b1,
        const float* __restrict__ b2, const float* __restrict__ b3,
        ushort_t* __restrict__ Bpk1, ushort_t* __restrict__ Bpk2,
        ushort_t* __restrict__ Bpk3, ushort_t* __restrict__ Bpk4,
        ushort_t* __restrict__ Bpk5, float* __restrict__ hbs,
        float* __restrict__ hbns) {
    int bid = blockIdx.x, tid = threadIdx.x;
    if (bid < 64) {
        const float* W; ushort_t* Bpk; int K, o;
        if (bid < 32)      { W = W1; Bpk = Bpk1; K = 128; o = bid * 256 + tid; }
        else if (bid < 48) { W = W2; Bpk = Bpk2; K = 64;  o = (bid - 32) * 256 + tid; }
        else               { W = W3; Bpk = Bpk3; K = 64;  o = (bid - 48) * 256 + tid; }
        int j = o & 7, c = (o >> 3) & 15, nf = (o >> 7) & 3, hi = (o >> 9) & 3,
            ks = o >> 11;
        Bpk[o] = f2bf(W[(nf * 16 + c) * K + ks * 32 + hi * 8 + j]);
    } else if (bid < 72) {
        int o = (bid - 64) * 256 + tid;
        int j = o & 7, c = (o >> 3) & 15, nf = (o >> 7) & 1, hi = (o >> 8) & 3,
            ks = o >> 10;
        Bpk4[o] = f2bf(W4[(nf * 16 + c) * 64 + ks * 32 + hi * 8 + j]);
    } else if (bid < 74) {
        int o = (bid - 72) * 256 + tid;
        if (o < 512) {
            int j = o & 7, c = (o >> 3) & 15, hi = o >> 7;
            Bpk5[o] = f2bf(W5[c * 32 + hi * 8 + j]);
        }
    } else {
        if (tid < 192) {
            int wv = tid >> 6, lane = tid & 63;
            const float* b = (wv == 0) ? b1 : (wv == 1) ? b2 : b3;
            float bv = b[lane];
            float bn = fmaxf(sqrtf(wave_sum(bv * bv)), 1e-15f);
            float th = fast_tanh(bn);
            float f = th / bn;
            float hn = th;
            if (th > 0.996f) { f = 0.996f / bn; hn = 0.996f; }
            hbs[wv * 64 + lane] = bv * f;
            if (lane == 0) hbns[wv] = hn;
        }
    }
}

// epilogue transform: HypLinear tail collapsed analytically (16-lane groups)
__device__ __forceinline__ void epi_row(const floatx4* acc, int r, float pn,
        float hbn, const float* __restrict__ hb, int c, float outv[4]) {
    float pp = 0.f;
#pragma unroll
    for (int nf = 0; nf < 4; ++nf) pp += acc[nf][r] * acc[nf][r];
#pragma unroll
    for (int m = 1; m < 16; m <<= 1) pp += __shfl_xor(pp, m, 64);
    float mpn = sqrtf(pp);
    float an = artanh_clip(pn);
    if (hbn <= 1e-15f) {
        float targ = (mpn / pn) * an;
        float scale = (targ > ATH996) ? (ATH996 / mpn) : (an / pn);
        if (mpn <= 1e-15f) scale = 0.f;
#pragma unroll
        for (int nf = 0; nf < 4; ++nf) outv[nf] = acc[nf][r] * scale;
    } else {
        float targ = (mpn / pn) * an;
        float th = fast_tanh(targ);
        float rn = fminf(th, 0.996f);
        float rs = (mpn <= 1e-15f) ? 0.f : (rn / mpn);
        float res[4], xyp = 0.f;
#pragma unroll
        for (int nf = 0; nf < 4; ++nf) {
            res[nf] = acc[nf][r] * rs;
            xyp += res[nf] * hb[nf * 16 + c];
        }
#pragma unroll
        for (int m = 1; m < 16; m <<= 1) xyp += __shfl_xor(xyp, m, 64);
        float x2 = rn * rn, y2 = hbn * hbn;
        float den = fmaxf(1.f + 2.f * xyp + x2 * y2, 1e-15f);
        float ca = (1.f + 2.f * xyp + y2) / den, cb = (1.f - x2) / den;
        float mv[4], mm = 0.f;
#pragma unroll
        for (int nf = 0; nf < 4; ++nf) {
            mv[nf] = ca * res[nf] + cb * hb[nf * 16 + c];
            mm += mv[nf] * mv[nf];
        }
#pragma unroll
        for (int m = 1; m < 16; m <<= 1) mm += __shfl_xor(mm, m, 64);
        float mn = sqrtf(mm);
        float mc = fminf(fmaxf(mn, 1e-15f), 0.996f);
        float msc = ((mn > 0.996f) ? (0.996f / mn) : 1.f) * artanh_clip(mc) / mc;
#pragma unroll
        for (int nf = 0; nf < 4; ++nf) outv[nf] = mv[nf] * msc;
    }
}

// layer 1 GEMM: x fp32 [N,128] -> (expmap0+proj fused) -> MFMA -> tail -> ht bf16
__global__ __launch_bounds__(256) void k_gemm1(
        const float* __restrict__ x, const ushort_t* __restrict__ Bpk,
        const float* __restrict__ hb, const float* __restrict__ hbn_p,
        ushort_t* __restrict__ htout, int n) {
    constexpr int RB = 256;
    __shared__ __align__(16) unsigned char As[64 * RB];
    __shared__ float pns[64];
    int tid = threadIdx.x, wv = tid >> 6, lane = tid & 63;
    int rowBase = blockIdx.x * 64;
#pragma unroll
    for (int it = 0; it < 16; ++it) {
        int row = wv * 16 + it, rg = rowBase + row;
        float2 v = make_float2(0.f, 0.f);
        if (rg < n) v = *(const float2*)(x + (size_t)rg * NFEAT + lane * 2);
        float ss = wave_sum(v.x * v.x + v.y * v.y);
        float nr = fmaxf(sqrtf(ss), 1e-15f);
        float th = fast_tanh(nr);
        float f = th / nr;
        float pn = fmaxf(th, 1e-15f);
        if (th > 0.996f) { f = 0.996f / nr; pn = 0.996f; }
        unsigned byte = (unsigned)(row * RB + lane * 4) ^ ((row & 7) << 4);
        *(unsigned*)(As + byte) = pack2(v.x * f, v.y * f);
        if (lane == 0) pns[row] = pn;
    }
    int hi = lane >> 4, c = lane & 15;
    short8 bf[4][4];
#pragma unroll
    for (int ks = 0; ks < 4; ++ks)
#pragma unroll
        for (int nf = 0; nf < 4; ++nf)
            bf[ks][nf] = *(const short8*)(Bpk + (((size_t)(ks * 4 + hi) * 4 + nf) * 16 + c) * 8);
    floatx4 acc[4];
#pragma unroll
    for (int nf = 0; nf < 4; ++nf)
#pragma unroll
        for (int r = 0; r < 4; ++r) acc[nf][r] = 0.f;
    int arow = wv * 16 + c;
#pragma unroll
    for (int ks = 0; ks < 4; ++ks) {
        unsigned byte = (unsigned)(arow * RB + ks * 64 + hi * 16) ^ ((arow & 7) << 4);
        short8 af = *(const short8*)(As + byte);
#pragma unroll
        for (int nf = 0; nf < 4; ++nf)
            acc[nf] = __builtin_amdgcn_mfma_f32_16x16x32_bf16(af, bf[ks][nf], acc[nf], 0, 0, 0);
    }
    float hbn = hbn_p[0];
#pragma unroll
    for (int r = 0; r < 4; ++r) {
        int row = wv * 16 + hi * 4 + r, rg = rowBase + row;
        float outv[4];
        epi_row(acc, r, pns[row], hbn, hb, c, outv);
        if (rg < n) {
#pragma unroll
            for (int nf = 0; nf < 4; ++nf)
                htout[(size_t)rg * 64 + nf * 16 + c] = f2bf(outv[nf]);
        }
    }
}

// layers 2/3 GEMM
__global__ __launch_bounds__(256) void k_gemm64(
        const ushort_t* __restrict__ h, const float* __restrict__ nrm_in,
        const ushort_t* __restrict__ Bpk, const float* __restrict__ hb,
        const float* __restrict__ hbn_p, ushort_t* __restrict__ htout, int n) {
    constexpr int RB = 128;
    __shared__ __align__(16) unsigned char As[64 * RB];
    int tid = threadIdx.x, wv = tid >> 6, lane = tid & 63;
    int rowBase = blockIdx.x * 64;
#pragma unroll
    for (int it = 0; it < 8; ++it) {
        int row = wv * 16 + it * 2 + (lane >> 5), rg = rowBase + row;
        int cl = lane & 31;
        unsigned pk = 0;
        if (rg < n) pk = *(const unsigned*)(h + (size_t)rg * 64 + cl * 2);
        unsigned byte = (unsigned)(row * RB + cl * 4) ^ ((row & 7) << 4);
        *(unsigned*)(As + byte) = pk;
    }
    int hi = lane >> 4, c = lane & 15;
    short8 bf[2][4];
#pragma unroll
    for (int ks = 0; ks < 2; ++ks)
#pragma unroll
        for (int nf = 0; nf < 4; ++nf)
            bf[ks][nf] = *(const short8*)(Bpk + (((size_t)(ks * 4 + hi) * 4 + nf) * 16 + c) * 8);
    floatx4 acc[4];
#pragma unroll
    for (int nf = 0; nf < 4; ++nf)
#pragma unroll
        for (int r = 0; r < 4; ++r) acc[nf][r] = 0.f;
    int arow = wv * 16 + c;
#pragma unroll
    for (int ks = 0; ks < 2; ++ks) {
        unsigned byte = (unsigned)(arow * RB + ks * 64 + hi * 16) ^ ((arow & 7) << 4);
        short8 af = *(const short8*)(As + byte);
#pragma unroll
        for (int nf = 0; nf < 4; ++nf)
            acc[nf] = __builtin_amdgcn_mfma_f32_16x16x32_bf16(af, bf[ks][nf], acc[nf], 0, 0, 0);
    }
    float hbn = hbn_p[0];
#pragma unroll
    for (int r = 0; r < 4; ++r) {
        int row = wv * 16 + hi * 4 + r, rg = rowBase + row;
        float pn = (rg < n) ? nrm_in[rg] : 1e-15f;
        float outv[4];
        epi_row(acc, r, pn, hbn, hb, c, outv);
        if (rg < n) {
#pragma unroll
            for (int nf = 0; nf < 4; ++nf)
                htout[(size_t)rg * 64 + nf * 16 + c] = f2bf(outv[nf]);
        }
    }
}

// CSR aggregation (bf16 gathers, 8-deep ILP, packed 4B edges) + HypAct
template <bool TANGENT_OUT>
__global__ __launch_bounds__(256) void k_agg_act(
        const ushort_t* __restrict__ ht, const int* __restrict__ off8,
        const unsigned* __restrict__ pe, ushort_t* __restrict__ hout,
        float* __restrict__ nrm_out, int n) {
    int wv = threadIdx.x >> 6, lane = threadIdx.x & 63;
    int node = blockIdx.x * 4 + wv;
    if (node >= n) return;
    node = __builtin_amdgcn_readfirstlane(node);
    int beg = off8[(size_t)node << 3], end = off8[((size_t)node << 3) + 8];
    float ac[8];
#pragma unroll
    for (int u = 0; u < 8; ++u) ac[u] = 0.f;
    int e = beg;
    for (; e + 7 < end; e += 8) {
        unsigned p[8];
#pragma unroll
        for (int u = 0; u < 8; ++u) p[u] = pe[e + u];
#pragma unroll
        for (int u = 0; u < 8; ++u)
            ac[u] = fmaf(pe_adj(p[u]),
                         bf2f(ht[(size_t)(p[u] >> 15) * 64 + lane]), ac[u]);
    }
    for (; e < end; ++e) {
        unsigned p = pe[e];
        ac[0] = fmaf(pe_adj(p), bf2f(ht[(size_t)(p >> 15) * 64 + lane]), ac[0]);
    }
    float acc = ((ac[0] + ac[1]) + (ac[2] + ac[3])) +
                ((ac[4] + ac[5]) + (ac[6] + ac[7]));
    float un = fmaxf(sqrtf(wave_sum(acc * acc)), 1e-15f);
    float thu = fast_tanh(un);
    float pf = thu / un, pn = thu;
    if (thu > 0.996f) { pf = 0.996f / un; pn = 0.996f; }
    float pnc = fmaxf(pn, 1e-15f);
    float t = artanh_clip(pnc) / pnc * pf * acc;   // logmap0(proj(expmap0(acc)))
    t = fmaxf(t, 0.f);                              // relu
    float tn = fmaxf(sqrtf(wave_sum(t * t)), 1e-15f);
    if (TANGENT_OUT) {
        float o = (tn > ATH996) ? (ATH996 / tn) * t : t;
        hout[(size_t)node * 64 + lane] = f2bf(o);
    } else {
        float tht = fast_tanh(tn);
        float rf = tht / tn, rn = tht;
        if (tht > 0.996f) { rf = 0.996f / tn; rn = 0.996f; }
        hout[(size_t)node * 64 + lane] = f2bf(rf * t);
        if (lane == 0) nrm_out[node] = fmaxf(rn, 1e-15f);
    }
}

// MFMA head: z = relu(t@W4.T+b4); out = log_softmax(z@W5.T+b5)
__global__ __launch_bounds__(256) void k_head(
        const ushort_t* __restrict__ t_in, const ushort_t* __restrict__ Bpk4,
        const float* __restrict__ b4, const ushort_t* __restrict__ Bpk5,
        const float* __restrict__ b5, float* __restrict__ out, int n) {
    constexpr int RB = 128;
    __shared__ __align__(16) unsigned char As[64 * RB];
    __shared__ __align__(16) unsigned char Zs[4][16 * 80];  // 80B rows: 2-way max
    int tid = threadIdx.x, wv = tid >> 6, lane = tid & 63;
    int rowBase = blockIdx.x * 64;
#pragma unroll
    for (int it = 0; it < 8; ++it) {
        int row = wv * 16 + it * 2 + (lane >> 5), rg = rowBase + row;
        int cl = lane & 31;
        unsigned pk = 0;
        if (rg < n) pk = *(const unsigned*)(t_in + (size_t)rg * 64 + cl * 2);
        unsigned byte = (unsigned)(row * RB + cl * 4) ^ ((row & 7) << 4);
        *(unsigned*)(As + byte) = pk;
    }
    int hi = lane >> 4, c = lane & 15;
    short8 bf4[2][2];
#pragma unroll
    for (int ks = 0; ks < 2; ++ks)
#pragma unroll
        for (int nf = 0; nf < 2; ++nf)
            bf4[ks][nf] = *(const short8*)(Bpk4 + (((size_t)(ks * 4 + hi) * 2 + nf) * 16 + c) * 8);
    floatx4 acc[2];
#pragma unroll
    for (int nf = 0; nf < 2; ++nf)
#pragma unroll
        for (int r = 0; r < 4; ++r) acc[nf][r] = 0.f;
    int arow = wv * 16 + c;
#pragma unroll
    for (int ks = 0; ks < 2; ++ks) {
        unsigned byte = (unsigned)(arow * RB + ks * 64 + hi * 16) ^ ((arow & 7) << 4);
        short8 af = *(const short8*)(As + byte);
#pragma unroll
        for (int nf = 0; nf < 2; ++nf)
            acc[nf] = __builtin_amdgcn_mfma_f32_16x16x32_bf16(af, bf4[ks][nf], acc[nf], 0, 0, 0);
    }
    float bb0 = b4[c], bb1 = b4[16 + c];
#pragma unroll
    for (int r = 0; r < 4; ++r) {
        int zr = hi * 4 + r;
        *(ushort_t*)(Zs[wv] + zr * 80 + c * 2) = f2bf(fmaxf(acc[0][r] + bb0, 0.f));
        *(ushort_t*)(Zs[wv] + zr * 80 + (16 + c) * 2) = f2bf(fmaxf(acc[1][r] + bb1, 0.f));
    }
    short8 bf5 = *(const short8*)(Bpk5 + ((size_t)(hi * 16 + c)) * 8);
    short8 zf = *(const short8*)(Zs[wv] + c * 80 + hi * 16);
    floatx4 acc5;
#pragma unroll
    for (int r = 0; r < 4; ++r) acc5[r] = 0.f;
    acc5 = __builtin_amdgcn_mfma_f32_16x16x32_bf16(zf, bf5, acc5, 0, 0, 0);
    float b5v = b5[c];
#pragma unroll
    for (int r = 0; r < 4; ++r) {
        float y = acc5[r] + b5v;
        float mx = y;
#pragma unroll
        for (int mk = 1; mk < 16; mk <<= 1) mx = fmaxf(mx, __shfl_xor(mx, mk, 64));
        float sm = __expf(y - mx);
#pragma unroll
        for (int mk = 1; mk < 16; mk <<= 1) sm += __shfl_xor(sm, mk, 64);
        int rg = rowBase + wv * 16 + hi * 4 + r;
        if (rg < n) out[(size_t)rg * 16 + c] = y - mx - __logf(sm);
    }
}

extern "C" void kernel_launch(void* const* d_in, const int* in_sizes, int n_in,
                              void* d_out, int out_size, void* d_ws, size_t ws_size,
                              hipStream_t stream) {
    const float* x   = (const float*)d_in[0];
    const int*   src = (const int*)d_in[1];
    const int*   dst = (const int*)d_in[2];
    const float* adj = (const float*)d_in[3];
    const float* W1  = (const float*)d_in[4];  const float* b1 = (const float*)d_in[5];
    const float* W2  = (const float*)d_in[6];  const float* b2 = (const float*)d_in[7];
    const float* W3  = (const float*)d_in[8];  const float* b3 = (const float*)d_in[9];
    const float* W4  = (const float*)d_in[10]; const float* b4 = (const float*)d_in[11];
    const float* W5  = (const float*)d_in[12]; const float* b5 = (const float*)d_in[13];
    float* out = (float*)d_out;

    const int N = in_sizes[0] / NFEAT;
    const int E = in_sizes[1];
    const int M = N * 8;                // sharded histogram cells

    // ws layout
    int* off8  = (int*)d_ws;            // M+1  (CSR offsets per (node,shard))
    int* cnt8  = off8 + (M + 1);        // M    (shard-major histogram)
    int* bsums = cnt8 + M;              // 1024
    int* lr    = bsums + 1024;          // E
    unsigned* pe = (unsigned*)(lr + E); // E packed edges (sorted by dst)
    ushort_t* B = (ushort_t*)(pe + E);                  // ht  bf16 [N,64]
    ushort_t* D = B + (size_t)N * 64;                   // h/t bf16 [N,64]
    float* nrm  = (float*)(D + (size_t)N * 64);         // ||h|| fp32 [N]
    float* hbs  = nrm + N;              // 3*64
    float* hbns = hbs + 192;            // 3 (+1 pad)
    ushort_t* Bpk1 = (ushort_t*)(hbns + 4);             // 8192
    ushort_t* Bpk2 = Bpk1 + 8192;                       // 4096
    ushort_t* Bpk3 = Bpk2 + 4096;                       // 4096
    ushort_t* Bpk4 = Bpk3 + 4096;                       // 2048
    ushort_t* Bpk5 = Bpk4 + 2048;                       // 512

    dim3 blk(256);
    int nodeBlocks = (N + 3) / 4;
    int gemmBlocks = (N + 63) / 64;
    int edgeThBlocks = (E + 255) / 256;
    int nb = (M + SCAN_B - 1) / SCAN_B;

    // prep (weights+bias in one launch) + CSR build
    k_prep<<<75, blk, 0, stream>>>(W1, W2, W3, W4, W5, b1, b2, b3,
                                   Bpk1, Bpk2, Bpk3, Bpk4, Bpk5, hbs, hbns);
    hipMemsetAsync(cnt8, 0, (size_t)M * sizeof(int), stream);
    k_rank<<<edgeThBlocks, blk, 0, stream>>>(dst, cnt8, lr, E, N);
    k_scan1<<<nb, blk, 0, stream>>>(cnt8, off8, bsums, M, N);
    k_scan2<<<1, blk, 0, stream>>>(bsums, nb, off8, M);
    k_scan3<<<(M + 255) / 256, blk, 0, stream>>>(off8, bsums, M);
    k_build<<<edgeThBlocks, blk, 0, stream>>>(dst, src, adj, off8, lr, pe, E);

    // layer 1
    k_gemm1<<<gemmBlocks, blk, 0, stream>>>(x, Bpk1, hbs, hbns, B, N);
    k_agg_act<false><<<nodeBlocks, blk, 0, stream>>>(B, off8, pe, D, nrm, N);
    // layer 2
    k_gemm64<<<gemmBlocks, blk, 0, stream>>>(D, nrm, Bpk2, hbs + 64, hbns + 1, B, N);
    k_agg_act<false><<<nodeBlocks, blk, 0, stream>>>(B, off8, pe, D, nrm, N);
    // layer 3
    k_gemm64<<<gemmBlocks, blk, 0, stream>>>(D, nrm, Bpk3, hbs + 128, hbns + 2, B, N);
    k_agg_act<true><<<nodeBlocks, blk, 0, stream>>>(B, off8, pe, D, nullptr, N);

    // head (MFMA)
    k_head<<<gemmBlocks, blk, 0, stream>>>(D, Bpk4, b4, Bpk5, b5, out, N);
}

// Round 9
// 271.645 us; speedup vs baseline: 1.3690x; 1.3690x over previous
//
#include <hip/hip_runtime.h>
#include <hip/hip_bf16.h>
#include <hip/hip_fp16.h>
#include <math.h>

#define NFEAT 128
#define NHID  64
#define SCAN_B 1024
#define ATH996 3.106303f   // artanh(0.996)

typedef __attribute__((ext_vector_type(8))) short short8;
typedef __attribute__((ext_vector_type(4))) float floatx4;
typedef unsigned short ushort_t;

__device__ __forceinline__ float wave_sum(float v) {
#pragma unroll
    for (int m = 1; m < 64; m <<= 1) v += __shfl_xor(v, m, 64);
    return v;
}

__device__ __forceinline__ float fast_tanh(float x) {
    float e = __expf(2.f * x);
    return 1.f - 2.f / (e + 1.f);
}

__device__ __forceinline__ float artanh_clip(float v) {
    const float lim = 0.99999988f;  // float(1 - 1e-7)
    v = fminf(fmaxf(v, -lim), lim);
    return 0.5f * __logf((1.f + v) / (1.f - v));
}

__device__ __forceinline__ unsigned pack2(float a, float b) {
    __hip_bfloat16 x = __float2bfloat16(a), y = __float2bfloat16(b);
    ushort_t ux = *(ushort_t*)&x, uy = *(ushort_t*)&y;
    return (unsigned)ux | ((unsigned)uy << 16);
}

__device__ __forceinline__ float bf2f(ushort_t u) {
    return __uint_as_float(((unsigned)u) << 16);
}
__device__ __forceinline__ ushort_t f2bf(float f) {
    __hip_bfloat16 h = __float2bfloat16(f);
    return *(ushort_t*)&h;
}

// packed edge: bits[31:15] = src (17b), bits[14:0] = fp16(adj) sans sign
__device__ __forceinline__ float pe_adj(unsigned p) {
    return __half2float(__ushort_as_half((ushort_t)(p & 0x7fffu)));
}

// ---- scans ------------------------------------------------------------------

__global__ __launch_bounds__(256) void k_scan1(const int* __restrict__ cnt,
        int* __restrict__ off, int* __restrict__ bsums, int n) {
    __shared__ int s[256];
    int tid = threadIdx.x;
    int base = blockIdx.x * SCAN_B + tid * 4;
    int c0 = 0, c1 = 0, c2 = 0, c3 = 0;
    if (base + 0 < n) c0 = cnt[base + 0];
    if (base + 1 < n) c1 = cnt[base + 1];
    if (base + 2 < n) c2 = cnt[base + 2];
    if (base + 3 < n) c3 = cnt[base + 3];
    int tsum = c0 + c1 + c2 + c3;
    s[tid] = tsum; __syncthreads();
    for (int o = 1; o < 256; o <<= 1) {
        int v = (tid >= o) ? s[tid - o] : 0;
        __syncthreads();
        s[tid] += v;
        __syncthreads();
    }
    int excl = s[tid] - tsum;
    if (base + 0 < n) off[base + 0] = excl;
    if (base + 1 < n) off[base + 1] = excl + c0;
    if (base + 2 < n) off[base + 2] = excl + c0 + c1;
    if (base + 3 < n) off[base + 3] = excl + c0 + c1 + c2;
    if (tid == 255) bsums[blockIdx.x] = s[255];
}

__global__ __launch_bounds__(256) void k_scan2(int* __restrict__ bsums, int nb,
                                               int* __restrict__ off, int ntot) {
    __shared__ int s[256];
    int tid = threadIdx.x;
    int base = tid * 4;
    int c0 = 0, c1 = 0, c2 = 0, c3 = 0;
    if (base + 0 < nb) c0 = bsums[base + 0];
    if (base + 1 < nb) c1 = bsums[base + 1];
    if (base + 2 < nb) c2 = bsums[base + 2];
    if (base + 3 < nb) c3 = bsums[base + 3];
    int tsum = c0 + c1 + c2 + c3;
    s[tid] = tsum; __syncthreads();
    for (int o = 1; o < 256; o <<= 1) {
        int v = (tid >= o) ? s[tid - o] : 0;
        __syncthreads();
        s[tid] += v;
        __syncthreads();
    }
    int excl = s[tid] - tsum;
    if (base + 0 < nb) bsums[base + 0] = excl;
    if (base + 1 < nb) bsums[base + 1] = excl + c0;
    if (base + 2 < nb) bsums[base + 2] = excl + c0 + c1;
    if (base + 3 < nb) bsums[base + 3] = excl + c0 + c1 + c2;
    if (tid == 255) off[ntot] = s[255];
}

__global__ __launch_bounds__(256) void k_scan3(int* __restrict__ off,
        const int* __restrict__ bsums, int n) {
    int i = blockIdx.x * 256 + threadIdx.x;
    if (i < n) off[i] += bsums[i >> 10];
}

// fused build+gather: scatter packed (src|fp16 adj) directly to final slot
__global__ __launch_bounds__(256) void k_build(const int* __restrict__ dst,
        const int* __restrict__ src, const float* __restrict__ adj,
        const int* __restrict__ off, const int* __restrict__ lr,
        unsigned* __restrict__ pe, int e) {
    int i = blockIdx.x * 256 + threadIdx.x;
    if (i < e) {
        int pos = off[dst[i]] + lr[i];
        unsigned ab = (unsigned)__half_as_ushort(__float2half(adj[i])) & 0x7fffu;
        pe[pos] = ((unsigned)src[i] << 15) | ab;
    }
}

// ---- one-shot prep: weight packs + biases + cnt zeroing ---------------------
// blocks 0-31: W1 | 32-47: W2 | 48-63: W3 | 64-71: W4 | 72-73: W5 | 74: biases
// blocks >=75: zero cnt
__global__ __launch_bounds__(256) void k_prep(
        const float* __restrict__ W1, const float* __restrict__ W2,
        const float* __restrict__ W3, const float* __restrict__ W4,
        const float* __restrict__ W5, const float* __restrict__ b1,
        const float* __restrict__ b2, const float* __restrict__ b3,
        ushort_t* __restrict__ Bpk1, ushort_t* __restrict__ Bpk2,
        ushort_t* __restrict__ Bpk3, ushort_t* __restrict__ Bpk4,
        ushort_t* __restrict__ Bpk5, float* __restrict__ hbs,
        float* __restrict__ hbns, int* __restrict__ cnt, int n) {
    int bid = blockIdx.x, tid = threadIdx.x;
    if (bid >= 75) {
        int i = (bid - 75) * 256 + tid;
        if (i < n) cnt[i] = 0;
        return;
    }
    if (bid < 64) {
        const float* W; ushort_t* Bpk; int K, o;
        if (bid < 32)      { W = W1; Bpk = Bpk1; K = 128; o = bid * 256 + tid; }
        else if (bid < 48) { W = W2; Bpk = Bpk2; K = 64;  o = (bid - 32) * 256 + tid; }
        else               { W = W3; Bpk = Bpk3; K = 64;  o = (bid - 48) * 256 + tid; }
        int j = o & 7, c = (o >> 3) & 15, nf = (o >> 7) & 3, hi = (o >> 9) & 3,
            ks = o >> 11;
        Bpk[o] = f2bf(W[(nf * 16 + c) * K + ks * 32 + hi * 8 + j]);
    } else if (bid < 72) {
        int o = (bid - 64) * 256 + tid;
        int j = o & 7, c = (o >> 3) & 15, nf = (o >> 7) & 1, hi = (o >> 8) & 3,
            ks = o >> 10;
        Bpk4[o] = f2bf(W4[(nf * 16 + c) * 64 + ks * 32 + hi * 8 + j]);
    } else if (bid < 74) {
        int o = (bid - 72) * 256 + tid;
        if (o < 512) {
            int j = o & 7, c = (o >> 3) & 15, hi = o >> 7;
            Bpk5[o] = f2bf(W5[c * 32 + hi * 8 + j]);
        }
    } else {
        if (tid < 192) {
            int wv = tid >> 6, lane = tid & 63;
            const float* b = (wv == 0) ? b1 : (wv == 1) ? b2 : b3;
            float bv = b[lane];
            float bn = fmaxf(sqrtf(wave_sum(bv * bv)), 1e-15f);
            float th = fast_tanh(bn);
            float f = th / bn;
            float hn = th;
            if (th > 0.996f) { f = 0.996f / bn; hn = 0.996f; }
            hbs[wv * 64 + lane] = bv * f;
            if (lane == 0) hbns[wv] = hn;
        }
    }
}

// epilogue transform: HypLinear tail collapsed analytically (16-lane groups)
__device__ __forceinline__ void epi_row(const floatx4* acc, int r, float pn,
        float hbn, const float* __restrict__ hb, int c, float outv[4]) {
    float pp = 0.f;
#pragma unroll
    for (int nf = 0; nf < 4; ++nf) pp += acc[nf][r] * acc[nf][r];
#pragma unroll
    for (int m = 1; m < 16; m <<= 1) pp += __shfl_xor(pp, m, 64);
    float mpn = sqrtf(pp);
    float an = artanh_clip(pn);
    if (hbn <= 1e-15f) {
        float targ = (mpn / pn) * an;
        float scale = (targ > ATH996) ? (ATH996 / mpn) : (an / pn);
        if (mpn <= 1e-15f) scale = 0.f;
#pragma unroll
        for (int nf = 0; nf < 4; ++nf) outv[nf] = acc[nf][r] * scale;
    } else {
        float targ = (mpn / pn) * an;
        float th = fast_tanh(targ);
        float rn = fminf(th, 0.996f);
        float rs = (mpn <= 1e-15f) ? 0.f : (rn / mpn);
        float res[4], xyp = 0.f;
#pragma unroll
        for (int nf = 0; nf < 4; ++nf) {
            res[nf] = acc[nf][r] * rs;
            xyp += res[nf] * hb[nf * 16 + c];
        }
#pragma unroll
        for (int m = 1; m < 16; m <<= 1) xyp += __shfl_xor(xyp, m, 64);
        float x2 = rn * rn, y2 = hbn * hbn;
        float den = fmaxf(1.f + 2.f * xyp + x2 * y2, 1e-15f);
        float ca = (1.f + 2.f * xyp + y2) / den, cb = (1.f - x2) / den;
        float mv[4], mm = 0.f;
#pragma unroll
        for (int nf = 0; nf < 4; ++nf) {
            mv[nf] = ca * res[nf] + cb * hb[nf * 16 + c];
            mm += mv[nf] * mv[nf];
        }
#pragma unroll
        for (int m = 1; m < 16; m <<= 1) mm += __shfl_xor(mm, m, 64);
        float mn = sqrtf(mm);
        float mc = fminf(fmaxf(mn, 1e-15f), 0.996f);
        float msc = ((mn > 0.996f) ? (0.996f / mn) : 1.f) * artanh_clip(mc) / mc;
#pragma unroll
        for (int nf = 0; nf < 4; ++nf) outv[nf] = mv[nf] * msc;
    }
}

// fused: blocks [0, gBlocks) run layer-1 GEMM; blocks >= gBlocks run edge rank.
// The two are independent; co-scheduling hides the GEMM under the atomic pass.
__global__ __launch_bounds__(256) void k_rank_gemm1(
        const float* __restrict__ x, const ushort_t* __restrict__ Bpk,
        const float* __restrict__ hb, const float* __restrict__ hbn_p,
        ushort_t* __restrict__ htout, int n, int gBlocks,
        const int* __restrict__ dst, int* __restrict__ cnt,
        int* __restrict__ lr, int e) {
    int tid = threadIdx.x;
    if ((int)blockIdx.x >= gBlocks) {
        int i = ((int)blockIdx.x - gBlocks) * 256 + tid;
        if (i < e) lr[i] = atomicAdd(&cnt[dst[i]], 1);
        return;
    }
    constexpr int RB = 256;
    __shared__ __align__(16) unsigned char As[64 * RB];
    __shared__ float pns[64];
    int wv = tid >> 6, lane = tid & 63;
    int rowBase = blockIdx.x * 64;
#pragma unroll
    for (int it = 0; it < 16; ++it) {
        int row = wv * 16 + it, rg = rowBase + row;
        float2 v = make_float2(0.f, 0.f);
        if (rg < n) v = *(const float2*)(x + (size_t)rg * NFEAT + lane * 2);
        float ss = wave_sum(v.x * v.x + v.y * v.y);
        float nr = fmaxf(sqrtf(ss), 1e-15f);
        float th = fast_tanh(nr);
        float f = th / nr;
        float pn = fmaxf(th, 1e-15f);
        if (th > 0.996f) { f = 0.996f / nr; pn = 0.996f; }
        unsigned byte = (unsigned)(row * RB + lane * 4) ^ ((row & 7) << 4);
        *(unsigned*)(As + byte) = pack2(v.x * f, v.y * f);
        if (lane == 0) pns[row] = pn;
    }
    int hi = lane >> 4, c = lane & 15;
    short8 bf[4][4];
#pragma unroll
    for (int ks = 0; ks < 4; ++ks)
#pragma unroll
        for (int nf = 0; nf < 4; ++nf)
            bf[ks][nf] = *(const short8*)(Bpk + (((size_t)(ks * 4 + hi) * 4 + nf) * 16 + c) * 8);
    floatx4 acc[4];
#pragma unroll
    for (int nf = 0; nf < 4; ++nf)
#pragma unroll
        for (int r = 0; r < 4; ++r) acc[nf][r] = 0.f;
    int arow = wv * 16 + c;
#pragma unroll
    for (int ks = 0; ks < 4; ++ks) {
        unsigned byte = (unsigned)(arow * RB + ks * 64 + hi * 16) ^ ((arow & 7) << 4);
        short8 af = *(const short8*)(As + byte);
#pragma unroll
        for (int nf = 0; nf < 4; ++nf)
            acc[nf] = __builtin_amdgcn_mfma_f32_16x16x32_bf16(af, bf[ks][nf], acc[nf], 0, 0, 0);
    }
    float hbn = hbn_p[0];
#pragma unroll
    for (int r = 0; r < 4; ++r) {
        int row = wv * 16 + hi * 4 + r, rg = rowBase + row;
        float outv[4];
        epi_row(acc, r, pns[row], hbn, hb, c, outv);
        if (rg < n) {
#pragma unroll
            for (int nf = 0; nf < 4; ++nf)
                htout[(size_t)rg * 64 + nf * 16 + c] = f2bf(outv[nf]);
        }
    }
}

// layers 2/3 GEMM
__global__ __launch_bounds__(256) void k_gemm64(
        const ushort_t* __restrict__ h, const float* __restrict__ nrm_in,
        const ushort_t* __restrict__ Bpk, const float* __restrict__ hb,
        const float* __restrict__ hbn_p, ushort_t* __restrict__ htout, int n) {
    constexpr int RB = 128;
    __shared__ __align__(16) unsigned char As[64 * RB];
    int tid = threadIdx.x, wv = tid >> 6, lane = tid & 63;
    int rowBase = blockIdx.x * 64;
#pragma unroll
    for (int it = 0; it < 8; ++it) {
        int row = wv * 16 + it * 2 + (lane >> 5), rg = rowBase + row;
        int cl = lane & 31;
        unsigned pk = 0;
        if (rg < n) pk = *(const unsigned*)(h + (size_t)rg * 64 + cl * 2);
        unsigned byte = (unsigned)(row * RB + cl * 4) ^ ((row & 7) << 4);
        *(unsigned*)(As + byte) = pk;
    }
    int hi = lane >> 4, c = lane & 15;
    short8 bf[2][4];
#pragma unroll
    for (int ks = 0; ks < 2; ++ks)
#pragma unroll
        for (int nf = 0; nf < 4; ++nf)
            bf[ks][nf] = *(const short8*)(Bpk + (((size_t)(ks * 4 + hi) * 4 + nf) * 16 + c) * 8);
    floatx4 acc[4];
#pragma unroll
    for (int nf = 0; nf < 4; ++nf)
#pragma unroll
        for (int r = 0; r < 4; ++r) acc[nf][r] = 0.f;
    int arow = wv * 16 + c;
#pragma unroll
    for (int ks = 0; ks < 2; ++ks) {
        unsigned byte = (unsigned)(arow * RB + ks * 64 + hi * 16) ^ ((arow & 7) << 4);
        short8 af = *(const short8*)(As + byte);
#pragma unroll
        for (int nf = 0; nf < 4; ++nf)
            acc[nf] = __builtin_amdgcn_mfma_f32_16x16x32_bf16(af, bf[ks][nf], acc[nf], 0, 0, 0);
    }
    float hbn = hbn_p[0];
#pragma unroll
    for (int r = 0; r < 4; ++r) {
        int row = wv * 16 + hi * 4 + r, rg = rowBase + row;
        float pn = (rg < n) ? nrm_in[rg] : 1e-15f;
        float outv[4];
        epi_row(acc, r, pn, hbn, hb, c, outv);
        if (rg < n) {
#pragma unroll
            for (int nf = 0; nf < 4; ++nf)
                htout[(size_t)rg * 64 + nf * 16 + c] = f2bf(outv[nf]);
        }
    }
}

// CSR aggregation + HypAct. 16 lanes per node (4 nodes/wave); each lane owns
// 4 features via one dwordx2 gather per edge; 4-deep edge ILP per node.
template <bool TANGENT_OUT>
__global__ __launch_bounds__(256) void k_agg_act(
        const ushort_t* __restrict__ ht, const int* __restrict__ off,
        const unsigned* __restrict__ pe, ushort_t* __restrict__ hout,
        float* __restrict__ nrm_out, int n) {
    int tid = threadIdx.x;
    int grp = tid >> 4, l = tid & 15;
    int node = blockIdx.x * 16 + grp;
    if (node >= n) return;
    int beg = off[node], end = off[node + 1];
    const char* hb8 = (const char*)ht + l * 8;   // lane's 8B feature column
    float a0[4] = {0.f, 0.f, 0.f, 0.f};
    float a1[4] = {0.f, 0.f, 0.f, 0.f};
    float a2[4] = {0.f, 0.f, 0.f, 0.f};
    float a3[4] = {0.f, 0.f, 0.f, 0.f};
    int e = beg;
    for (; e + 3 < end; e += 4) {
        unsigned p0 = pe[e], p1 = pe[e + 1], p2 = pe[e + 2], p3 = pe[e + 3];
        uint2 r0 = *(const uint2*)(hb8 + ((size_t)(p0 >> 15) << 7));
        uint2 r1 = *(const uint2*)(hb8 + ((size_t)(p1 >> 15) << 7));
        uint2 r2 = *(const uint2*)(hb8 + ((size_t)(p2 >> 15) << 7));
        uint2 r3 = *(const uint2*)(hb8 + ((size_t)(p3 >> 15) << 7));
        float w0 = pe_adj(p0), w1 = pe_adj(p1), w2 = pe_adj(p2), w3 = pe_adj(p3);
        a0[0] = fmaf(w0, __uint_as_float(r0.x << 16), a0[0]);
        a0[1] = fmaf(w0, __uint_as_float(r0.x & 0xffff0000u), a0[1]);
        a0[2] = fmaf(w0, __uint_as_float(r0.y << 16), a0[2]);
        a0[3] = fmaf(w0, __uint_as_float(r0.y & 0xffff0000u), a0[3]);
        a1[0] = fmaf(w1, __uint_as_float(r1.x << 16), a1[0]);
        a1[1] = fmaf(w1, __uint_as_float(r1.x & 0xffff0000u), a1[1]);
        a1[2] = fmaf(w1, __uint_as_float(r1.y << 16), a1[2]);
        a1[3] = fmaf(w1, __uint_as_float(r1.y & 0xffff0000u), a1[3]);
        a2[0] = fmaf(w2, __uint_as_float(r2.x << 16), a2[0]);
        a2[1] = fmaf(w2, __uint_as_float(r2.x & 0xffff0000u), a2[1]);
        a2[2] = fmaf(w2, __uint_as_float(r2.y << 16), a2[2]);
        a2[3] = fmaf(w2, __uint_as_float(r2.y & 0xffff0000u), a2[3]);
        a3[0] = fmaf(w3, __uint_as_float(r3.x << 16), a3[0]);
        a3[1] = fmaf(w3, __uint_as_float(r3.x & 0xffff0000u), a3[1]);
        a3[2] = fmaf(w3, __uint_as_float(r3.y << 16), a3[2]);
        a3[3] = fmaf(w3, __uint_as_float(r3.y & 0xffff0000u), a3[3]);
    }
    for (; e < end; ++e) {
        unsigned p = pe[e];
        uint2 r = *(const uint2*)(hb8 + ((size_t)(p >> 15) << 7));
        float w = pe_adj(p);
        a0[0] = fmaf(w, __uint_as_float(r.x << 16), a0[0]);
        a0[1] = fmaf(w, __uint_as_float(r.x & 0xffff0000u), a0[1]);
        a0[2] = fmaf(w, __uint_as_float(r.y << 16), a0[2]);
        a0[3] = fmaf(w, __uint_as_float(r.y & 0xffff0000u), a0[3]);
    }
    float f0 = (a0[0] + a1[0]) + (a2[0] + a3[0]);
    float f1 = (a0[1] + a1[1]) + (a2[1] + a3[1]);
    float f2 = (a0[2] + a1[2]) + (a2[2] + a3[2]);
    float f3 = (a0[3] + a1[3]) + (a2[3] + a3[3]);
    float ss = f0 * f0 + f1 * f1 + f2 * f2 + f3 * f3;
#pragma unroll
    for (int m = 1; m < 16; m <<= 1) ss += __shfl_xor(ss, m, 64);
    float un = fmaxf(sqrtf(ss), 1e-15f);
    float thu = fast_tanh(un);
    float pf = thu / un, pn = thu;
    if (thu > 0.996f) { pf = 0.996f / un; pn = 0.996f; }
    float pnc = fmaxf(pn, 1e-15f);
    float ls = artanh_clip(pnc) / pnc * pf;   // logmap0(proj(expmap0(.))) scale
    float t0 = fmaxf(ls * f0, 0.f), t1 = fmaxf(ls * f1, 0.f);
    float t2 = fmaxf(ls * f2, 0.f), t3 = fmaxf(ls * f3, 0.f);
    float ss2 = t0 * t0 + t1 * t1 + t2 * t2 + t3 * t3;
#pragma unroll
    for (int m = 1; m < 16; m <<= 1) ss2 += __shfl_xor(ss2, m, 64);
    float tn = fmaxf(sqrtf(ss2), 1e-15f);
    uint2 ov;
    if (TANGENT_OUT) {
        float sc = (tn > ATH996) ? (ATH996 / tn) : 1.f;
        ov = make_uint2(pack2(t0 * sc, t1 * sc), pack2(t2 * sc, t3 * sc));
    } else {
        float tht = fast_tanh(tn);
        float rf = tht / tn, rn = tht;
        if (tht > 0.996f) { rf = 0.996f / tn; rn = 0.996f; }
        ov = make_uint2(pack2(rf * t0, rf * t1), pack2(rf * t2, rf * t3));
        if (l == 0) nrm_out[node] = fmaxf(rn, 1e-15f);
    }
    *(uint2*)((char*)hout + (size_t)node * 128 + l * 8) = ov;
}

// MFMA head: z = relu(t@W4.T+b4); out = log_softmax(z@W5.T+b5)
__global__ __launch_bounds__(256) void k_head(
        const ushort_t* __restrict__ t_in, const ushort_t* __restrict__ Bpk4,
        const float* __restrict__ b4, const ushort_t* __restrict__ Bpk5,
        const float* __restrict__ b5, float* __restrict__ out, int n) {
    constexpr int RB = 128;
    __shared__ __align__(16) unsigned char As[64 * RB];
    __shared__ __align__(16) unsigned char Zs[4][16 * 80];  // 80B rows: 2-way max
    int tid = threadIdx.x, wv = tid >> 6, lane = tid & 63;
    int rowBase = blockIdx.x * 64;
#pragma unroll
    for (int it = 0; it < 8; ++it) {
        int row = wv * 16 + it * 2 + (lane >> 5), rg = rowBase + row;
        int cl = lane & 31;
        unsigned pk = 0;
        if (rg < n) pk = *(const unsigned*)(t_in + (size_t)rg * 64 + cl * 2);
        unsigned byte = (unsigned)(row * RB + cl * 4) ^ ((row & 7) << 4);
        *(unsigned*)(As + byte) = pk;
    }
    int hi = lane >> 4, c = lane & 15;
    short8 bf4[2][2];
#pragma unroll
    for (int ks = 0; ks < 2; ++ks)
#pragma unroll
        for (int nf = 0; nf < 2; ++nf)
            bf4[ks][nf] = *(const short8*)(Bpk4 + (((size_t)(ks * 4 + hi) * 2 + nf) * 16 + c) * 8);
    floatx4 acc[2];
#pragma unroll
    for (int nf = 0; nf < 2; ++nf)
#pragma unroll
        for (int r = 0; r < 4; ++r) acc[nf][r] = 0.f;
    int arow = wv * 16 + c;
#pragma unroll
    for (int ks = 0; ks < 2; ++ks) {
        unsigned byte = (unsigned)(arow * RB + ks * 64 + hi * 16) ^ ((arow & 7) << 4);
        short8 af = *(const short8*)(As + byte);
#pragma unroll
        for (int nf = 0; nf < 2; ++nf)
            acc[nf] = __builtin_amdgcn_mfma_f32_16x16x32_bf16(af, bf4[ks][nf], acc[nf], 0, 0, 0);
    }
    float bb0 = b4[c], bb1 = b4[16 + c];
#pragma unroll
    for (int r = 0; r < 4; ++r) {
        int zr = hi * 4 + r;
        *(ushort_t*)(Zs[wv] + zr * 80 + c * 2) = f2bf(fmaxf(acc[0][r] + bb0, 0.f));
        *(ushort_t*)(Zs[wv] + zr * 80 + (16 + c) * 2) = f2bf(fmaxf(acc[1][r] + bb1, 0.f));
    }
    short8 bf5 = *(const short8*)(Bpk5 + ((size_t)(hi * 16 + c)) * 8);
    short8 zf = *(const short8*)(Zs[wv] + c * 80 + hi * 16);
    floatx4 acc5;
#pragma unroll
    for (int r = 0; r < 4; ++r) acc5[r] = 0.f;
    acc5 = __builtin_amdgcn_mfma_f32_16x16x32_bf16(zf, bf5, acc5, 0, 0, 0);
    float b5v = b5[c];
#pragma unroll
    for (int r = 0; r < 4; ++r) {
        float y = acc5[r] + b5v;
        float mx = y;
#pragma unroll
        for (int mk = 1; mk < 16; mk <<= 1) mx = fmaxf(mx, __shfl_xor(mx, mk, 64));
        float sm = __expf(y - mx);
#pragma unroll
        for (int mk = 1; mk < 16; mk <<= 1) sm += __shfl_xor(sm, mk, 64);
        int rg = rowBase + wv * 16 + hi * 4 + r;
        if (rg < n) out[(size_t)rg * 16 + c] = y - mx - __logf(sm);
    }
}

extern "C" void kernel_launch(void* const* d_in, const int* in_sizes, int n_in,
                              void* d_out, int out_size, void* d_ws, size_t ws_size,
                              hipStream_t stream) {
    const float* x   = (const float*)d_in[0];
    const int*   src = (const int*)d_in[1];
    const int*   dst = (const int*)d_in[2];
    const float* adj = (const float*)d_in[3];
    const float* W1  = (const float*)d_in[4];  const float* b1 = (const float*)d_in[5];
    const float* W2  = (const float*)d_in[6];  const float* b2 = (const float*)d_in[7];
    const float* W3  = (const float*)d_in[8];  const float* b3 = (const float*)d_in[9];
    const float* W4  = (const float*)d_in[10]; const float* b4 = (const float*)d_in[11];
    const float* W5  = (const float*)d_in[12]; const float* b5 = (const float*)d_in[13];
    float* out = (float*)d_out;

    const int N = in_sizes[0] / NFEAT;
    const int E = in_sizes[1];

    // ws layout, every region 256B-aligned (uint2/short8 access safety)
    char* w = (char*)d_ws;
    auto alloc = [&](size_t bytes) {
        char* p = w; w += (bytes + 255) & ~(size_t)255; return p;
    };
    int* off   = (int*)alloc((size_t)(N + 1) * 4);
    int* cnt   = (int*)alloc((size_t)N * 4);
    int* bsums = (int*)alloc(1024 * 4);
    int* lr    = (int*)alloc((size_t)E * 4);
    unsigned* pe = (unsigned*)alloc((size_t)E * 4);
    ushort_t* B  = (ushort_t*)alloc((size_t)N * 64 * 2);
    ushort_t* D  = (ushort_t*)alloc((size_t)N * 64 * 2);
    float* nrm   = (float*)alloc((size_t)N * 4);
    float* hbs   = (float*)alloc(192 * 4);
    float* hbns  = (float*)alloc(4 * 4);
    ushort_t* Bpk1 = (ushort_t*)alloc(8192 * 2);
    ushort_t* Bpk2 = (ushort_t*)alloc(4096 * 2);
    ushort_t* Bpk3 = (ushort_t*)alloc(4096 * 2);
    ushort_t* Bpk4 = (ushort_t*)alloc(2048 * 2);
    ushort_t* Bpk5 = (ushort_t*)alloc(512 * 2);

    dim3 blk(256);
    int aggBlocks = (N + 15) / 16;
    int gemmBlocks = (N + 63) / 64;
    int edgeThBlocks = (E + 255) / 256;
    int nb = (N + SCAN_B - 1) / SCAN_B;

    // prep (weight packs + biases + cnt zeroing, one launch)
    k_prep<<<75 + (N + 255) / 256, blk, 0, stream>>>(
        W1, W2, W3, W4, W5, b1, b2, b3,
        Bpk1, Bpk2, Bpk3, Bpk4, Bpk5, hbs, hbns, cnt, N);

    // fused: layer-1 GEMM || edge rank (independent)
    k_rank_gemm1<<<gemmBlocks + edgeThBlocks, blk, 0, stream>>>(
        x, Bpk1, hbs, hbns, B, N, gemmBlocks, dst, cnt, lr, E);

    // CSR offsets + edge scatter
    k_scan1<<<nb, blk, 0, stream>>>(cnt, off, bsums, N);
    k_scan2<<<1, blk, 0, stream>>>(bsums, nb, off, N);
    k_scan3<<<(N + 255) / 256, blk, 0, stream>>>(off, bsums, N);
    k_build<<<edgeThBlocks, blk, 0, stream>>>(dst, src, adj, off, lr, pe, E);

    // layer 1 aggregation (+act)
    k_agg_act<false><<<aggBlocks, blk, 0, stream>>>(B, off, pe, D, nrm, N);
    // layer 2
    k_gemm64<<<gemmBlocks, blk, 0, stream>>>(D, nrm, Bpk2, hbs + 64, hbns + 1, B, N);
    k_agg_act<false><<<aggBlocks, blk, 0, stream>>>(B, off, pe, D, nrm, N);
    // layer 3
    k_gemm64<<<gemmBlocks, blk, 0, stream>>>(D, nrm, Bpk3, hbs + 128, hbns + 2, B, N);
    k_agg_act<true><<<aggBlocks, blk, 0, stream>>>(B, off, pe, D, nullptr, N);

    // head (MFMA)
    k_head<<<gemmBlocks, blk, 0, stream>>>(D, Bpk4, b4, Bpk5, b5, out, N);
}

// Round 10
// 236.918 us; speedup vs baseline: 1.5697x; 1.1466x over previous
//
#include <hip/hip_runtime.h>
#include <hip/hip_bf16.h>
#include <hip/hip_fp16.h>
#include <math.h>

#define NFEAT 128
#define NHID  64
#define ATH996 3.106303f   // artanh(0.996)
#define CHUNK 4096         // edges per sort block

typedef __attribute__((ext_vector_type(8))) short short8;
typedef __attribute__((ext_vector_type(4))) float floatx4;
typedef unsigned short ushort_t;
typedef unsigned long long u64;

__device__ __forceinline__ float wave_sum(float v) {
#pragma unroll
    for (int m = 1; m < 64; m <<= 1) v += __shfl_xor(v, m, 64);
    return v;
}

__device__ __forceinline__ float fast_tanh(float x) {
    float e = __expf(2.f * x);
    return 1.f - 2.f / (e + 1.f);
}

__device__ __forceinline__ float artanh_clip(float v) {
    const float lim = 0.99999988f;  // float(1 - 1e-7)
    v = fminf(fmaxf(v, -lim), lim);
    return 0.5f * __logf((1.f + v) / (1.f - v));
}

__device__ __forceinline__ unsigned pack2(float a, float b) {
    __hip_bfloat16 x = __float2bfloat16(a), y = __float2bfloat16(b);
    ushort_t ux = *(ushort_t*)&x, uy = *(ushort_t*)&y;
    return (unsigned)ux | ((unsigned)uy << 16);
}

__device__ __forceinline__ ushort_t f2bf(float f) {
    __hip_bfloat16 h = __float2bfloat16(f);
    return *(ushort_t*)&h;
}

// packed edge: bits[31:15] = src (17b), bits[14:0] = fp16(adj) sans sign
__device__ __forceinline__ float pe_adj(unsigned p) {
    return __half2float(__ushort_as_half((ushort_t)(p & 0x7fffu)));
}

// ---- bucketed CSR build (all per-edge atomics in LDS) -----------------------

// A: global bucket histogram via LDS pre-aggregation
__global__ __launch_bounds__(256) void k_bhist(const int* __restrict__ dst,
        int* __restrict__ gBktCnt, int e, int nb) {
    __shared__ int cnt[512];
    int tid = threadIdx.x;
    for (int t = tid; t < nb; t += 256) cnt[t] = 0;
    __syncthreads();
    int start = blockIdx.x * CHUNK, end = min(e, start + CHUNK);
    for (int i = start + tid; i < end; i += 256)
        atomicAdd(&cnt[dst[i] >> 8], 1);
    __syncthreads();
    for (int t = tid; t < nb; t += 256)
        if (cnt[t]) atomicAdd(&gBktCnt[t], cnt[t]);
}

// B: scan bucket counts -> bases + cursors; off[N]=E; sentinel base[nb]
__global__ __launch_bounds__(256) void k_bscan(const int* __restrict__ gBktCnt,
        int* __restrict__ gBktBase, int* __restrict__ gCur,
        int* __restrict__ off, int nb, int n, int e) {
    __shared__ int s[256];
    int tid = threadIdx.x;
    int base = tid * 4;
    int c0 = (base + 0 < nb) ? gBktCnt[base + 0] : 0;
    int c1 = (base + 1 < nb) ? gBktCnt[base + 1] : 0;
    int c2 = (base + 2 < nb) ? gBktCnt[base + 2] : 0;
    int c3 = (base + 3 < nb) ? gBktCnt[base + 3] : 0;
    int tsum = c0 + c1 + c2 + c3;
    s[tid] = tsum; __syncthreads();
    for (int o = 1; o < 256; o <<= 1) {
        int v = (tid >= o) ? s[tid - o] : 0;
        __syncthreads();
        s[tid] += v;
        __syncthreads();
    }
    int ex = s[tid] - tsum;
    int e0 = ex, e1 = ex + c0, e2 = ex + c0 + c1, e3 = ex + c0 + c1 + c2;
    if (base + 0 < nb) { gBktBase[base + 0] = e0; gCur[base + 0] = e0; }
    if (base + 1 < nb) { gBktBase[base + 1] = e1; gCur[base + 1] = e1; }
    if (base + 2 < nb) { gBktBase[base + 2] = e2; gCur[base + 2] = e2; }
    if (base + 3 < nb) { gBktBase[base + 3] = e3; gCur[base + 3] = e3; }
    if (tid == 255) gBktBase[nb] = s[255];
    if (tid == 0) off[n] = e;
}

// C: chunk-local counting sort by bucket; coalesced staged writes
__global__ __launch_bounds__(256) void k_bscatter(const int* __restrict__ dst,
        const int* __restrict__ src, const float* __restrict__ adj,
        int* __restrict__ gCur, u64* __restrict__ gStage, int e, int nb) {
    __shared__ u64 stage[CHUNK];
    __shared__ int cnt[512], excl[512], rcnt[512], myBase[512], s[256];
    int tid = threadIdx.x;
    int start = blockIdx.x * CHUNK, end = min(e, start + CHUNK);
    for (int t = tid; t < nb; t += 256) { cnt[t] = 0; rcnt[t] = 0; }
    __syncthreads();
    for (int i = start + tid; i < end; i += 256)
        atomicAdd(&cnt[dst[i] >> 8], 1);
    __syncthreads();
    // scan cnt[0..nb) -> excl, 2 elems/thread (nb <= 512)
    int v0 = (2 * tid < nb) ? cnt[2 * tid] : 0;
    int v1 = (2 * tid + 1 < nb) ? cnt[2 * tid + 1] : 0;
    int tsum = v0 + v1;
    s[tid] = tsum; __syncthreads();
    for (int o = 1; o < 256; o <<= 1) {
        int v = (tid >= o) ? s[tid - o] : 0;
        __syncthreads();
        s[tid] += v;
        __syncthreads();
    }
    int ex = s[tid] - tsum;
    if (2 * tid < nb) excl[2 * tid] = ex;
    if (2 * tid + 1 < nb) excl[2 * tid + 1] = ex + v0;
    __syncthreads();
    // claim global runs (1 atomic per non-empty bucket per block)
    for (int t = tid; t < nb; t += 256)
        if (cnt[t]) myBase[t] = atomicAdd(&gCur[t], cnt[t]);
    // fill stage in bucket-sorted order
    for (int i = start + tid; i < end; i += 256) {
        int d = dst[i];
        int b = d >> 8;
        unsigned ab = (unsigned)__half_as_ushort(__float2half(adj[i])) & 0x7fffu;
        u64 u = ((u64)(unsigned)d << 32) |
                (u64)(((unsigned)src[i] << 15) | ab);
        int r = atomicAdd(&rcnt[b], 1);
        stage[excl[b] + r] = u;
    }
    __syncthreads();
    // coalesced write-out: consecutive j in a bucket -> consecutive gpos
    int sz = end - start;
    for (int j = tid; j < sz; j += 256) {
        u64 u = stage[j];
        int b = (int)(u >> 40) & 0x1ff;   // dst>>8
        gStage[myBase[b] + (j - excl[b])] = u;
    }
}

// D: per-bucket finalize: local node histogram -> off[]; rank-scatter pe[]
__global__ __launch_bounds__(256) void k_bfinal(const u64* __restrict__ gStage,
        const int* __restrict__ gBktBase, int* __restrict__ off,
        unsigned* __restrict__ pe, int n) {
    __shared__ int ncnt[256], nexcl[256], rcnt[256], s[256];
    int tid = threadIdx.x, b = blockIdx.x;
    int ebeg = gBktBase[b], eend = gBktBase[b + 1];
    int nbeg = b << 8;
    ncnt[tid] = 0; rcnt[tid] = 0;
    __syncthreads();
    for (int j = ebeg + tid; j < eend; j += 256) {
        int dl = ((int)(gStage[j] >> 32) & 0x1ffff) - nbeg;
        atomicAdd(&ncnt[dl], 1);
    }
    __syncthreads();
    int v = ncnt[tid];
    s[tid] = v; __syncthreads();
    for (int o = 1; o < 256; o <<= 1) {
        int t2 = (tid >= o) ? s[tid - o] : 0;
        __syncthreads();
        s[tid] += t2;
        __syncthreads();
    }
    nexcl[tid] = s[tid] - v;
    if (nbeg + tid < n) off[nbeg + tid] = ebeg + nexcl[tid];
    __syncthreads();
    for (int j = ebeg + tid; j < eend; j += 256) {
        u64 u = gStage[j];
        int dl = ((int)(u >> 32) & 0x1ffff) - nbeg;
        int r = atomicAdd(&rcnt[dl], 1);
        pe[ebeg + nexcl[dl] + r] = (unsigned)u;
    }
}

// ---- one-shot prep: weight packs + biases + bucket-count zeroing ------------
__global__ __launch_bounds__(256) void k_prep(
        const float* __restrict__ W1, const float* __restrict__ W2,
        const float* __restrict__ W3, const float* __restrict__ W4,
        const float* __restrict__ W5, const float* __restrict__ b1,
        const float* __restrict__ b2, const float* __restrict__ b3,
        ushort_t* __restrict__ Bpk1, ushort_t* __restrict__ Bpk2,
        ushort_t* __restrict__ Bpk3, ushort_t* __restrict__ Bpk4,
        ushort_t* __restrict__ Bpk5, float* __restrict__ hbs,
        float* __restrict__ hbns, int* __restrict__ gBktCnt, int nb) {
    int bid = blockIdx.x, tid = threadIdx.x;
    if (bid >= 75) {
        for (int t = tid; t < nb; t += 256) gBktCnt[t] = 0;
        return;
    }
    if (bid < 64) {
        const float* W; ushort_t* Bpk; int K, o;
        if (bid < 32)      { W = W1; Bpk = Bpk1; K = 128; o = bid * 256 + tid; }
        else if (bid < 48) { W = W2; Bpk = Bpk2; K = 64;  o = (bid - 32) * 256 + tid; }
        else               { W = W3; Bpk = Bpk3; K = 64;  o = (bid - 48) * 256 + tid; }
        int j = o & 7, c = (o >> 3) & 15, nf = (o >> 7) & 3, hi = (o >> 9) & 3,
            ks = o >> 11;
        Bpk[o] = f2bf(W[(nf * 16 + c) * K + ks * 32 + hi * 8 + j]);
    } else if (bid < 72) {
        int o = (bid - 64) * 256 + tid;
        int j = o & 7, c = (o >> 3) & 15, nf = (o >> 7) & 1, hi = (o >> 8) & 3,
            ks = o >> 10;
        Bpk4[o] = f2bf(W4[(nf * 16 + c) * 64 + ks * 32 + hi * 8 + j]);
    } else if (bid < 74) {
        int o = (bid - 72) * 256 + tid;
        if (o < 512) {
            int j = o & 7, c = (o >> 3) & 15, hi = o >> 7;
            Bpk5[o] = f2bf(W5[c * 32 + hi * 8 + j]);
        }
    } else {
        if (tid < 192) {
            int wv = tid >> 6, lane = tid & 63;
            const float* b = (wv == 0) ? b1 : (wv == 1) ? b2 : b3;
            float bv = b[lane];
            float bn = fmaxf(sqrtf(wave_sum(bv * bv)), 1e-15f);
            float th = fast_tanh(bn);
            float f = th / bn;
            float hn = th;
            if (th > 0.996f) { f = 0.996f / bn; hn = 0.996f; }
            hbs[wv * 64 + lane] = bv * f;
            if (lane == 0) hbns[wv] = hn;
        }
    }
}

// epilogue transform: HypLinear tail collapsed analytically (16-lane groups)
__device__ __forceinline__ void epi_row(const floatx4* acc, int r, float pn,
        float hbn, const float* __restrict__ hb, int c, float outv[4]) {
    float pp = 0.f;
#pragma unroll
    for (int nf = 0; nf < 4; ++nf) pp += acc[nf][r] * acc[nf][r];
#pragma unroll
    for (int m = 1; m < 16; m <<= 1) pp += __shfl_xor(pp, m, 64);
    float mpn = sqrtf(pp);
    float an = artanh_clip(pn);
    if (hbn <= 1e-15f) {
        float targ = (mpn / pn) * an;
        float scale = (targ > ATH996) ? (ATH996 / mpn) : (an / pn);
        if (mpn <= 1e-15f) scale = 0.f;
#pragma unroll
        for (int nf = 0; nf < 4; ++nf) outv[nf] = acc[nf][r] * scale;
    } else {
        float targ = (mpn / pn) * an;
        float th = fast_tanh(targ);
        float rn = fminf(th, 0.996f);
        float rs = (mpn <= 1e-15f) ? 0.f : (rn / mpn);
        float res[4], xyp = 0.f;
#pragma unroll
        for (int nf = 0; nf < 4; ++nf) {
            res[nf] = acc[nf][r] * rs;
            xyp += res[nf] * hb[nf * 16 + c];
        }
#pragma unroll
        for (int m = 1; m < 16; m <<= 1) xyp += __shfl_xor(xyp, m, 64);
        float x2 = rn * rn, y2 = hbn * hbn;
        float den = fmaxf(1.f + 2.f * xyp + x2 * y2, 1e-15f);
        float ca = (1.f + 2.f * xyp + y2) / den, cb = (1.f - x2) / den;
        float mv[4], mm = 0.f;
#pragma unroll
        for (int nf = 0; nf < 4; ++nf) {
            mv[nf] = ca * res[nf] + cb * hb[nf * 16 + c];
            mm += mv[nf] * mv[nf];
        }
#pragma unroll
        for (int m = 1; m < 16; m <<= 1) mm += __shfl_xor(mm, m, 64);
        float mn = sqrtf(mm);
        float mc = fminf(fmaxf(mn, 1e-15f), 0.996f);
        float msc = ((mn > 0.996f) ? (0.996f / mn) : 1.f) * artanh_clip(mc) / mc;
#pragma unroll
        for (int nf = 0; nf < 4; ++nf) outv[nf] = mv[nf] * msc;
    }
}

// layer 1 GEMM: x fp32 [N,128] -> (expmap0+proj fused) -> MFMA -> tail -> ht bf16
__global__ __launch_bounds__(256) void k_gemm1(
        const float* __restrict__ x, const ushort_t* __restrict__ Bpk,
        const float* __restrict__ hb, const float* __restrict__ hbn_p,
        ushort_t* __restrict__ htout, int n) {
    constexpr int RB = 256;
    __shared__ __align__(16) unsigned char As[64 * RB];
    __shared__ float pns[64];
    int tid = threadIdx.x, wv = tid >> 6, lane = tid & 63;
    int rowBase = blockIdx.x * 64;
#pragma unroll
    for (int it = 0; it < 16; ++it) {
        int row = wv * 16 + it, rg = rowBase + row;
        float2 v = make_float2(0.f, 0.f);
        if (rg < n) v = *(const float2*)(x + (size_t)rg * NFEAT + lane * 2);
        float ss = wave_sum(v.x * v.x + v.y * v.y);
        float nr = fmaxf(sqrtf(ss), 1e-15f);
        float th = fast_tanh(nr);
        float f = th / nr;
        float pn = fmaxf(th, 1e-15f);
        if (th > 0.996f) { f = 0.996f / nr; pn = 0.996f; }
        unsigned byte = (unsigned)(row * RB + lane * 4) ^ ((row & 7) << 4);
        *(unsigned*)(As + byte) = pack2(v.x * f, v.y * f);
        if (lane == 0) pns[row] = pn;
    }
    int hi = lane >> 4, c = lane & 15;
    short8 bf[4][4];
#pragma unroll
    for (int ks = 0; ks < 4; ++ks)
#pragma unroll
        for (int nf = 0; nf < 4; ++nf)
            bf[ks][nf] = *(const short8*)(Bpk + (((size_t)(ks * 4 + hi) * 4 + nf) * 16 + c) * 8);
    floatx4 acc[4];
#pragma unroll
    for (int nf = 0; nf < 4; ++nf)
#pragma unroll
        for (int r = 0; r < 4; ++r) acc[nf][r] = 0.f;
    int arow = wv * 16 + c;
#pragma unroll
    for (int ks = 0; ks < 4; ++ks) {
        unsigned byte = (unsigned)(arow * RB + ks * 64 + hi * 16) ^ ((arow & 7) << 4);
        short8 af = *(const short8*)(As + byte);
#pragma unroll
        for (int nf = 0; nf < 4; ++nf)
            acc[nf] = __builtin_amdgcn_mfma_f32_16x16x32_bf16(af, bf[ks][nf], acc[nf], 0, 0, 0);
    }
    float hbn = hbn_p[0];
#pragma unroll
    for (int r = 0; r < 4; ++r) {
        int row = wv * 16 + hi * 4 + r, rg = rowBase + row;
        float outv[4];
        epi_row(acc, r, pns[row], hbn, hb, c, outv);
        if (rg < n) {
#pragma unroll
            for (int nf = 0; nf < 4; ++nf)
                htout[(size_t)rg * 64 + nf * 16 + c] = f2bf(outv[nf]);
        }
    }
}

// layers 2/3 GEMM
__global__ __launch_bounds__(256) void k_gemm64(
        const ushort_t* __restrict__ h, const float* __restrict__ nrm_in,
        const ushort_t* __restrict__ Bpk, const float* __restrict__ hb,
        const float* __restrict__ hbn_p, ushort_t* __restrict__ htout, int n) {
    constexpr int RB = 128;
    __shared__ __align__(16) unsigned char As[64 * RB];
    int tid = threadIdx.x, wv = tid >> 6, lane = tid & 63;
    int rowBase = blockIdx.x * 64;
#pragma unroll
    for (int it = 0; it < 8; ++it) {
        int row = wv * 16 + it * 2 + (lane >> 5), rg = rowBase + row;
        int cl = lane & 31;
        unsigned pk = 0;
        if (rg < n) pk = *(const unsigned*)(h + (size_t)rg * 64 + cl * 2);
        unsigned byte = (unsigned)(row * RB + cl * 4) ^ ((row & 7) << 4);
        *(unsigned*)(As + byte) = pk;
    }
    int hi = lane >> 4, c = lane & 15;
    short8 bf[2][4];
#pragma unroll
    for (int ks = 0; ks < 2; ++ks)
#pragma unroll
        for (int nf = 0; nf < 4; ++nf)
            bf[ks][nf] = *(const short8*)(Bpk + (((size_t)(ks * 4 + hi) * 4 + nf) * 16 + c) * 8);
    floatx4 acc[4];
#pragma unroll
    for (int nf = 0; nf < 4; ++nf)
#pragma unroll
        for (int r = 0; r < 4; ++r) acc[nf][r] = 0.f;
    int arow = wv * 16 + c;
#pragma unroll
    for (int ks = 0; ks < 2; ++ks) {
        unsigned byte = (unsigned)(arow * RB + ks * 64 + hi * 16) ^ ((arow & 7) << 4);
        short8 af = *(const short8*)(As + byte);
#pragma unroll
        for (int nf = 0; nf < 4; ++nf)
            acc[nf] = __builtin_amdgcn_mfma_f32_16x16x32_bf16(af, bf[ks][nf], acc[nf], 0, 0, 0);
    }
    float hbn = hbn_p[0];
#pragma unroll
    for (int r = 0; r < 4; ++r) {
        int row = wv * 16 + hi * 4 + r, rg = rowBase + row;
        float pn = (rg < n) ? nrm_in[rg] : 1e-15f;
        float outv[4];
        epi_row(acc, r, pn, hbn, hb, c, outv);
        if (rg < n) {
#pragma unroll
            for (int nf = 0; nf < 4; ++nf)
                htout[(size_t)rg * 64 + nf * 16 + c] = f2bf(outv[nf]);
        }
    }
}

// CSR aggregation + HypAct. 16 lanes per node (4 nodes/wave); each lane owns
// 4 features via one dwordx2 gather per edge; 4-deep edge ILP per node.
template <bool TANGENT_OUT>
__global__ __launch_bounds__(256) void k_agg_act(
        const ushort_t* __restrict__ ht, const int* __restrict__ off,
        const unsigned* __restrict__ pe, ushort_t* __restrict__ hout,
        float* __restrict__ nrm_out, int n) {
    int tid = threadIdx.x;
    int grp = tid >> 4, l = tid & 15;
    int node = blockIdx.x * 16 + grp;
    if (node >= n) return;
    int beg = off[node], end = off[node + 1];
    const char* hb8 = (const char*)ht + l * 8;   // lane's 8B feature column
    float a0[4] = {0.f, 0.f, 0.f, 0.f};
    float a1[4] = {0.f, 0.f, 0.f, 0.f};
    float a2[4] = {0.f, 0.f, 0.f, 0.f};
    float a3[4] = {0.f, 0.f, 0.f, 0.f};
    int e = beg;
    for (; e + 3 < end; e += 4) {
        unsigned p0 = pe[e], p1 = pe[e + 1], p2 = pe[e + 2], p3 = pe[e + 3];
        uint2 r0 = *(const uint2*)(hb8 + ((size_t)(p0 >> 15) << 7));
        uint2 r1 = *(const uint2*)(hb8 + ((size_t)(p1 >> 15) << 7));
        uint2 r2 = *(const uint2*)(hb8 + ((size_t)(p2 >> 15) << 7));
        uint2 r3 = *(const uint2*)(hb8 + ((size_t)(p3 >> 15) << 7));
        float w0 = pe_adj(p0), w1 = pe_adj(p1), w2 = pe_adj(p2), w3 = pe_adj(p3);
        a0[0] = fmaf(w0, __uint_as_float(r0.x << 16), a0[0]);
        a0[1] = fmaf(w0, __uint_as_float(r0.x & 0xffff0000u), a0[1]);
        a0[2] = fmaf(w0, __uint_as_float(r0.y << 16), a0[2]);
        a0[3] = fmaf(w0, __uint_as_float(r0.y & 0xffff0000u), a0[3]);
        a1[0] = fmaf(w1, __uint_as_float(r1.x << 16), a1[0]);
        a1[1] = fmaf(w1, __uint_as_float(r1.x & 0xffff0000u), a1[1]);
        a1[2] = fmaf(w1, __uint_as_float(r1.y << 16), a1[2]);
        a1[3] = fmaf(w1, __uint_as_float(r1.y & 0xffff0000u), a1[3]);
        a2[0] = fmaf(w2, __uint_as_float(r2.x << 16), a2[0]);
        a2[1] = fmaf(w2, __uint_as_float(r2.x & 0xffff0000u), a2[1]);
        a2[2] = fmaf(w2, __uint_as_float(r2.y << 16), a2[2]);
        a2[3] = fmaf(w2, __uint_as_float(r2.y & 0xffff0000u), a2[3]);
        a3[0] = fmaf(w3, __uint_as_float(r3.x << 16), a3[0]);
        a3[1] = fmaf(w3, __uint_as_float(r3.x & 0xffff0000u), a3[1]);
        a3[2] = fmaf(w3, __uint_as_float(r3.y << 16), a3[2]);
        a3[3] = fmaf(w3, __uint_as_float(r3.y & 0xffff0000u), a3[3]);
    }
    for (; e < end; ++e) {
        unsigned p = pe[e];
        uint2 r = *(const uint2*)(hb8 + ((size_t)(p >> 15) << 7));
        float w = pe_adj(p);
        a0[0] = fmaf(w, __uint_as_float(r.x << 16), a0[0]);
        a0[1] = fmaf(w, __uint_as_float(r.x & 0xffff0000u), a0[1]);
        a0[2] = fmaf(w, __uint_as_float(r.y << 16), a0[2]);
        a0[3] = fmaf(w, __uint_as_float(r.y & 0xffff0000u), a0[3]);
    }
    float f0 = (a0[0] + a1[0]) + (a2[0] + a3[0]);
    float f1 = (a0[1] + a1[1]) + (a2[1] + a3[1]);
    float f2 = (a0[2] + a1[2]) + (a2[2] + a3[2]);
    float f3 = (a0[3] + a1[3]) + (a2[3] + a3[3]);
    float ss = f0 * f0 + f1 * f1 + f2 * f2 + f3 * f3;
#pragma unroll
    for (int m = 1; m < 16; m <<= 1) ss += __shfl_xor(ss, m, 64);
    float un = fmaxf(sqrtf(ss), 1e-15f);
    float thu = fast_tanh(un);
    float pf = thu / un, pn = thu;
    if (thu > 0.996f) { pf = 0.996f / un; pn = 0.996f; }
    float pnc = fmaxf(pn, 1e-15f);
    float ls = artanh_clip(pnc) / pnc * pf;   // logmap0(proj(expmap0(.))) scale
    float t0 = fmaxf(ls * f0, 0.f), t1 = fmaxf(ls * f1, 0.f);
    float t2 = fmaxf(ls * f2, 0.f), t3 = fmaxf(ls * f3, 0.f);
    float ss2 = t0 * t0 + t1 * t1 + t2 * t2 + t3 * t3;
#pragma unroll
    for (int m = 1; m < 16; m <<= 1) ss2 += __shfl_xor(ss2, m, 64);
    float tn = fmaxf(sqrtf(ss2), 1e-15f);
    uint2 ov;
    if (TANGENT_OUT) {
        float sc = (tn > ATH996) ? (ATH996 / tn) : 1.f;
        ov = make_uint2(pack2(t0 * sc, t1 * sc), pack2(t2 * sc, t3 * sc));
    } else {
        float tht = fast_tanh(tn);
        float rf = tht / tn, rn = tht;
        if (tht > 0.996f) { rf = 0.996f / tn; rn = 0.996f; }
        ov = make_uint2(pack2(rf * t0, rf * t1), pack2(rf * t2, rf * t3));
        if (l == 0) nrm_out[node] = fmaxf(rn, 1e-15f);
    }
    *(uint2*)((char*)hout + (size_t)node * 128 + l * 8) = ov;
}

// MFMA head: z = relu(t@W4.T+b4); out = log_softmax(z@W5.T+b5)
__global__ __launch_bounds__(256) void k_head(
        const ushort_t* __restrict__ t_in, const ushort_t* __restrict__ Bpk4,
        const float* __restrict__ b4, const ushort_t* __restrict__ Bpk5,
        const float* __restrict__ b5, float* __restrict__ out, int n) {
    constexpr int RB = 128;
    __shared__ __align__(16) unsigned char As[64 * RB];
    __shared__ __align__(16) unsigned char Zs[4][16 * 80];  // 80B rows: 2-way max
    int tid = threadIdx.x, wv = tid >> 6, lane = tid & 63;
    int rowBase = blockIdx.x * 64;
#pragma unroll
    for (int it = 0; it < 8; ++it) {
        int row = wv * 16 + it * 2 + (lane >> 5), rg = rowBase + row;
        int cl = lane & 31;
        unsigned pk = 0;
        if (rg < n) pk = *(const unsigned*)(t_in + (size_t)rg * 64 + cl * 2);
        unsigned byte = (unsigned)(row * RB + cl * 4) ^ ((row & 7) << 4);
        *(unsigned*)(As + byte) = pk;
    }
    int hi = lane >> 4, c = lane & 15;
    short8 bf4[2][2];
#pragma unroll
    for (int ks = 0; ks < 2; ++ks)
#pragma unroll
        for (int nf = 0; nf < 2; ++nf)
            bf4[ks][nf] = *(const short8*)(Bpk4 + (((size_t)(ks * 4 + hi) * 2 + nf) * 16 + c) * 8);
    floatx4 acc[2];
#pragma unroll
    for (int nf = 0; nf < 2; ++nf)
#pragma unroll
        for (int r = 0; r < 4; ++r) acc[nf][r] = 0.f;
    int arow = wv * 16 + c;
#pragma unroll
    for (int ks = 0; ks < 2; ++ks) {
        unsigned byte = (unsigned)(arow * RB + ks * 64 + hi * 16) ^ ((arow & 7) << 4);
        short8 af = *(const short8*)(As + byte);
#pragma unroll
        for (int nf = 0; nf < 2; ++nf)
            acc[nf] = __builtin_amdgcn_mfma_f32_16x16x32_bf16(af, bf4[ks][nf], acc[nf], 0, 0, 0);
    }
    float bb0 = b4[c], bb1 = b4[16 + c];
#pragma unroll
    for (int r = 0; r < 4; ++r) {
        int zr = hi * 4 + r;
        *(ushort_t*)(Zs[wv] + zr * 80 + c * 2) = f2bf(fmaxf(acc[0][r] + bb0, 0.f));
        *(ushort_t*)(Zs[wv] + zr * 80 + (16 + c) * 2) = f2bf(fmaxf(acc[1][r] + bb1, 0.f));
    }
    short8 bf5 = *(const short8*)(Bpk5 + ((size_t)(hi * 16 + c)) * 8);
    short8 zf = *(const short8*)(Zs[wv] + c * 80 + hi * 16);
    floatx4 acc5;
#pragma unroll
    for (int r = 0; r < 4; ++r) acc5[r] = 0.f;
    acc5 = __builtin_amdgcn_mfma_f32_16x16x32_bf16(zf, bf5, acc5, 0, 0, 0);
    float b5v = b5[c];
#pragma unroll
    for (int r = 0; r < 4; ++r) {
        float y = acc5[r] + b5v;
        float mx = y;
#pragma unroll
        for (int mk = 1; mk < 16; mk <<= 1) mx = fmaxf(mx, __shfl_xor(mx, mk, 64));
        float sm = __expf(y - mx);
#pragma unroll
        for (int mk = 1; mk < 16; mk <<= 1) sm += __shfl_xor(sm, mk, 64);
        int rg = rowBase + wv * 16 + hi * 4 + r;
        if (rg < n) out[(size_t)rg * 16 + c] = y - mx - __logf(sm);
    }
}

extern "C" void kernel_launch(void* const* d_in, const int* in_sizes, int n_in,
                              void* d_out, int out_size, void* d_ws, size_t ws_size,
                              hipStream_t stream) {
    const float* x   = (const float*)d_in[0];
    const int*   src = (const int*)d_in[1];
    const int*   dst = (const int*)d_in[2];
    const float* adj = (const float*)d_in[3];
    const float* W1  = (const float*)d_in[4];  const float* b1 = (const float*)d_in[5];
    const float* W2  = (const float*)d_in[6];  const float* b2 = (const float*)d_in[7];
    const float* W3  = (const float*)d_in[8];  const float* b3 = (const float*)d_in[9];
    const float* W4  = (const float*)d_in[10]; const float* b4 = (const float*)d_in[11];
    const float* W5  = (const float*)d_in[12]; const float* b5 = (const float*)d_in[13];
    float* out = (float*)d_out;

    const int N = in_sizes[0] / NFEAT;
    const int E = in_sizes[1];
    const int NB = (N + 255) >> 8;   // 256-node buckets (<= 512)

    // ws layout, every region 256B-aligned
    char* w = (char*)d_ws;
    auto alloc = [&](size_t bytes) {
        char* p = w; w += (bytes + 255) & ~(size_t)255; return p;
    };
    int* off      = (int*)alloc((size_t)(N + 1) * 4);
    int* gBktCnt  = (int*)alloc((size_t)NB * 4);
    int* gBktBase = (int*)alloc((size_t)(NB + 1) * 4);
    int* gCur     = (int*)alloc((size_t)NB * 4);
    u64* gStage   = (u64*)alloc((size_t)E * 8);
    unsigned* pe  = (unsigned*)alloc((size_t)E * 4);
    ushort_t* B   = (ushort_t*)alloc((size_t)N * 64 * 2);
    ushort_t* D   = (ushort_t*)alloc((size_t)N * 64 * 2);
    float* nrm    = (float*)alloc((size_t)N * 4);
    float* hbs    = (float*)alloc(192 * 4);
    float* hbns   = (float*)alloc(4 * 4);
    ushort_t* Bpk1 = (ushort_t*)alloc(8192 * 2);
    ushort_t* Bpk2 = (ushort_t*)alloc(4096 * 2);
    ushort_t* Bpk3 = (ushort_t*)alloc(4096 * 2);
    ushort_t* Bpk4 = (ushort_t*)alloc(2048 * 2);
    ushort_t* Bpk5 = (ushort_t*)alloc(512 * 2);

    dim3 blk(256);
    int aggBlocks  = (N + 15) / 16;
    int gemmBlocks = (N + 63) / 64;
    int sortBlocks = (E + CHUNK - 1) / CHUNK;

    // prep: weight packs + biases + bucket-count zeroing
    k_prep<<<76, blk, 0, stream>>>(W1, W2, W3, W4, W5, b1, b2, b3,
                                   Bpk1, Bpk2, Bpk3, Bpk4, Bpk5, hbs, hbns,
                                   gBktCnt, NB);

    // layer-1 GEMM (independent of CSR)
    k_gemm1<<<gemmBlocks, blk, 0, stream>>>(x, Bpk1, hbs, hbns, B, N);

    // bucketed CSR build: LDS-atomic two-level counting sort
    k_bhist<<<sortBlocks, blk, 0, stream>>>(dst, gBktCnt, E, NB);
    k_bscan<<<1, blk, 0, stream>>>(gBktCnt, gBktBase, gCur, off, NB, N, E);
    k_bscatter<<<sortBlocks, blk, 0, stream>>>(dst, src, adj, gCur, gStage, E, NB);
    k_bfinal<<<NB, blk, 0, stream>>>(gStage, gBktBase, off, pe, N);

    // layer 1 aggregation (+act)
    k_agg_act<false><<<aggBlocks, blk, 0, stream>>>(B, off, pe, D, nrm, N);
    // layer 2
    k_gemm64<<<gemmBlocks, blk, 0, stream>>>(D, nrm, Bpk2, hbs + 64, hbns + 1, B, N);
    k_agg_act<false><<<aggBlocks, blk, 0, stream>>>(B, off, pe, D, nrm, N);
    // layer 3
    k_gemm64<<<gemmBlocks, blk, 0, stream>>>(D, nrm, Bpk3, hbs + 128, hbns + 2, B, N);
    k_agg_act<true><<<aggBlocks, blk, 0, stream>>>(B, off, pe, D, nullptr, N);

    // head (MFMA)
    k_head<<<gemmBlocks, blk, 0, stream>>>(D, Bpk4, b4, Bpk5, b5, out, N);
}

// Round 11
// 218.663 us; speedup vs baseline: 1.7007x; 1.0835x over previous
//
#include <hip/hip_runtime.h>
#include <hip/hip_bf16.h>
#include <hip/hip_fp16.h>
#include <math.h>

#define NFEAT 128
#define NHID  64
#define ATH996 3.106303f   // artanh(0.996)
#define CHUNK 4096         // edges per sort block

typedef __attribute__((ext_vector_type(8))) short short8;
typedef __attribute__((ext_vector_type(4))) float floatx4;
typedef unsigned short ushort_t;
typedef unsigned long long u64;

__device__ __forceinline__ float wave_sum(float v) {
#pragma unroll
    for (int m = 1; m < 64; m <<= 1) v += __shfl_xor(v, m, 64);
    return v;
}

__device__ __forceinline__ float fast_tanh(float x) {
    float e = __expf(2.f * x);
    return 1.f - 2.f / (e + 1.f);
}

__device__ __forceinline__ float artanh_clip(float v) {
    const float lim = 0.99999988f;  // float(1 - 1e-7)
    v = fminf(fmaxf(v, -lim), lim);
    return 0.5f * __logf((1.f + v) / (1.f - v));
}

__device__ __forceinline__ unsigned pack2(float a, float b) {
    __hip_bfloat16 x = __float2bfloat16(a), y = __float2bfloat16(b);
    ushort_t ux = *(ushort_t*)&x, uy = *(ushort_t*)&y;
    return (unsigned)ux | ((unsigned)uy << 16);
}

__device__ __forceinline__ ushort_t f2bf(float f) {
    __hip_bfloat16 h = __float2bfloat16(f);
    return *(ushort_t*)&h;
}

// packed edge: bits[31:15] = src (17b), bits[14:0] = fp16(adj) sans sign
__device__ __forceinline__ float pe_adj(unsigned p) {
    return __half2float(__ushort_as_half((ushort_t)(p & 0x7fffu)));
}

// ---- bucketed CSR build (all per-edge atomics in LDS) -----------------------

// B: scan bucket counts -> bases + cursors; off[N]=E; sentinel base[nb]
__global__ __launch_bounds__(256) void k_bscan(const int* __restrict__ gBktCnt,
        int* __restrict__ gBktBase, int* __restrict__ gCur,
        int* __restrict__ off, int nb, int n, int e) {
    __shared__ int s[256];
    int tid = threadIdx.x;
    int base = tid * 4;
    int c0 = (base + 0 < nb) ? gBktCnt[base + 0] : 0;
    int c1 = (base + 1 < nb) ? gBktCnt[base + 1] : 0;
    int c2 = (base + 2 < nb) ? gBktCnt[base + 2] : 0;
    int c3 = (base + 3 < nb) ? gBktCnt[base + 3] : 0;
    int tsum = c0 + c1 + c2 + c3;
    s[tid] = tsum; __syncthreads();
    for (int o = 1; o < 256; o <<= 1) {
        int v = (tid >= o) ? s[tid - o] : 0;
        __syncthreads();
        s[tid] += v;
        __syncthreads();
    }
    int ex = s[tid] - tsum;
    int e0 = ex, e1 = ex + c0, e2 = ex + c0 + c1, e3 = ex + c0 + c1 + c2;
    if (base + 0 < nb) { gBktBase[base + 0] = e0; gCur[base + 0] = e0; }
    if (base + 1 < nb) { gBktBase[base + 1] = e1; gCur[base + 1] = e1; }
    if (base + 2 < nb) { gBktBase[base + 2] = e2; gCur[base + 2] = e2; }
    if (base + 3 < nb) { gBktBase[base + 3] = e3; gCur[base + 3] = e3; }
    if (tid == 255) gBktBase[nb] = s[255];
    if (tid == 0) off[n] = e;
}

// C: chunk-local counting sort by bucket; coalesced staged writes
__global__ __launch_bounds__(256) void k_bscatter(const int* __restrict__ dst,
        const int* __restrict__ src, const float* __restrict__ adj,
        int* __restrict__ gCur, u64* __restrict__ gStage, int e, int nb) {
    __shared__ u64 stage[CHUNK];
    __shared__ int cnt[512], excl[512], rcnt[512], myBase[512], s[256];
    int tid = threadIdx.x;
    int start = blockIdx.x * CHUNK, end = min(e, start + CHUNK);
    for (int t = tid; t < nb; t += 256) { cnt[t] = 0; rcnt[t] = 0; }
    __syncthreads();
    for (int i = start + tid; i < end; i += 256)
        atomicAdd(&cnt[dst[i] >> 8], 1);
    __syncthreads();
    int v0 = (2 * tid < nb) ? cnt[2 * tid] : 0;
    int v1 = (2 * tid + 1 < nb) ? cnt[2 * tid + 1] : 0;
    int tsum = v0 + v1;
    s[tid] = tsum; __syncthreads();
    for (int o = 1; o < 256; o <<= 1) {
        int v = (tid >= o) ? s[tid - o] : 0;
        __syncthreads();
        s[tid] += v;
        __syncthreads();
    }
    int ex = s[tid] - tsum;
    if (2 * tid < nb) excl[2 * tid] = ex;
    if (2 * tid + 1 < nb) excl[2 * tid + 1] = ex + v0;
    __syncthreads();
    for (int t = tid; t < nb; t += 256)
        if (cnt[t]) myBase[t] = atomicAdd(&gCur[t], cnt[t]);
    for (int i = start + tid; i < end; i += 256) {
        int d = dst[i];
        int b = d >> 8;
        unsigned ab = (unsigned)__half_as_ushort(__float2half(adj[i])) & 0x7fffu;
        u64 u = ((u64)(unsigned)d << 32) |
                (u64)(((unsigned)src[i] << 15) | ab);
        int r = atomicAdd(&rcnt[b], 1);
        stage[excl[b] + r] = u;
    }
    __syncthreads();
    int sz = end - start;
    for (int j = tid; j < sz; j += 256) {
        u64 u = stage[j];
        int b = (int)(u >> 40) & 0x1ff;   // dst>>8
        gStage[myBase[b] + (j - excl[b])] = u;
    }
}

// D: per-bucket finalize: local node histogram -> off[]; rank-scatter pe[]
__global__ __launch_bounds__(256) void k_bfinal(const u64* __restrict__ gStage,
        const int* __restrict__ gBktBase, int* __restrict__ off,
        unsigned* __restrict__ pe, int n) {
    __shared__ int ncnt[256], nexcl[256], rcnt[256], s[256];
    int tid = threadIdx.x, b = blockIdx.x;
    int ebeg = gBktBase[b], eend = gBktBase[b + 1];
    int nbeg = b << 8;
    ncnt[tid] = 0; rcnt[tid] = 0;
    __syncthreads();
    for (int j = ebeg + tid; j < eend; j += 256) {
        int dl = ((int)(gStage[j] >> 32) & 0x1ffff) - nbeg;
        atomicAdd(&ncnt[dl], 1);
    }
    __syncthreads();
    int v = ncnt[tid];
    s[tid] = v; __syncthreads();
    for (int o = 1; o < 256; o <<= 1) {
        int t2 = (tid >= o) ? s[tid - o] : 0;
        __syncthreads();
        s[tid] += t2;
        __syncthreads();
    }
    nexcl[tid] = s[tid] - v;
    if (nbeg + tid < n) off[nbeg + tid] = ebeg + nexcl[tid];
    __syncthreads();
    for (int j = ebeg + tid; j < eend; j += 256) {
        u64 u = gStage[j];
        int dl = ((int)(u >> 32) & 0x1ffff) - nbeg;
        int r = atomicAdd(&rcnt[dl], 1);
        pe[ebeg + nexcl[dl] + r] = (unsigned)u;
    }
}

// ---- one-shot prep: weight packs + biases + bucket-count zeroing ------------
__global__ __launch_bounds__(256) void k_prep(
        const float* __restrict__ W1, const float* __restrict__ W2,
        const float* __restrict__ W3, const float* __restrict__ W4,
        const float* __restrict__ W5, const float* __restrict__ b1,
        const float* __restrict__ b2, const float* __restrict__ b3,
        ushort_t* __restrict__ Bpk1, ushort_t* __restrict__ Bpk2,
        ushort_t* __restrict__ Bpk3, ushort_t* __restrict__ Bpk4,
        ushort_t* __restrict__ Bpk5, float* __restrict__ hbs,
        float* __restrict__ hbns, int* __restrict__ gBktCnt, int nb) {
    int bid = blockIdx.x, tid = threadIdx.x;
    if (bid >= 75) {
        for (int t = tid; t < nb; t += 256) gBktCnt[t] = 0;
        return;
    }
    if (bid < 64) {
        const float* W; ushort_t* Bpk; int K, o;
        if (bid < 32)      { W = W1; Bpk = Bpk1; K = 128; o = bid * 256 + tid; }
        else if (bid < 48) { W = W2; Bpk = Bpk2; K = 64;  o = (bid - 32) * 256 + tid; }
        else               { W = W3; Bpk = Bpk3; K = 64;  o = (bid - 48) * 256 + tid; }
        int j = o & 7, c = (o >> 3) & 15, nf = (o >> 7) & 3, hi = (o >> 9) & 3,
            ks = o >> 11;
        Bpk[o] = f2bf(W[(nf * 16 + c) * K + ks * 32 + hi * 8 + j]);
    } else if (bid < 72) {
        int o = (bid - 64) * 256 + tid;
        int j = o & 7, c = (o >> 3) & 15, nf = (o >> 7) & 1, hi = (o >> 8) & 3,
            ks = o >> 10;
        Bpk4[o] = f2bf(W4[(nf * 16 + c) * 64 + ks * 32 + hi * 8 + j]);
    } else if (bid < 74) {
        int o = (bid - 72) * 256 + tid;
        if (o < 512) {
            int j = o & 7, c = (o >> 3) & 15, hi = o >> 7;
            Bpk5[o] = f2bf(W5[c * 32 + hi * 8 + j]);
        }
    } else {
        if (tid < 192) {
            int wv = tid >> 6, lane = tid & 63;
            const float* b = (wv == 0) ? b1 : (wv == 1) ? b2 : b3;
            float bv = b[lane];
            float bn = fmaxf(sqrtf(wave_sum(bv * bv)), 1e-15f);
            float th = fast_tanh(bn);
            float f = th / bn;
            float hn = th;
            if (th > 0.996f) { f = 0.996f / bn; hn = 0.996f; }
            hbs[wv * 64 + lane] = bv * f;
            if (lane == 0) hbns[wv] = hn;
        }
    }
}

// epilogue transform on one row's 4 nf-values (16-lane-group reductions)
__device__ __forceinline__ void epi_vals(const float vin[4], float pn,
        float hbn, const float* __restrict__ hb, int c, float outv[4]) {
    float pp = 0.f;
#pragma unroll
    for (int nf = 0; nf < 4; ++nf) pp += vin[nf] * vin[nf];
#pragma unroll
    for (int m = 1; m < 16; m <<= 1) pp += __shfl_xor(pp, m, 64);
    float mpn = sqrtf(pp);
    float an = artanh_clip(pn);
    if (hbn <= 1e-15f) {
        float targ = (mpn / pn) * an;
        float scale = (targ > ATH996) ? (ATH996 / mpn) : (an / pn);
        if (mpn <= 1e-15f) scale = 0.f;
#pragma unroll
        for (int nf = 0; nf < 4; ++nf) outv[nf] = vin[nf] * scale;
    } else {
        float targ = (mpn / pn) * an;
        float th = fast_tanh(targ);
        float rn = fminf(th, 0.996f);
        float rs = (mpn <= 1e-15f) ? 0.f : (rn / mpn);
        float res[4], xyp = 0.f;
#pragma unroll
        for (int nf = 0; nf < 4; ++nf) {
            res[nf] = vin[nf] * rs;
            xyp += res[nf] * hb[nf * 16 + c];
        }
#pragma unroll
        for (int m = 1; m < 16; m <<= 1) xyp += __shfl_xor(xyp, m, 64);
        float x2 = rn * rn, y2 = hbn * hbn;
        float den = fmaxf(1.f + 2.f * xyp + x2 * y2, 1e-15f);
        float ca = (1.f + 2.f * xyp + y2) / den, cb = (1.f - x2) / den;
        float mv[4], mm = 0.f;
#pragma unroll
        for (int nf = 0; nf < 4; ++nf) {
            mv[nf] = ca * res[nf] + cb * hb[nf * 16 + c];
            mm += mv[nf] * mv[nf];
        }
#pragma unroll
        for (int m = 1; m < 16; m <<= 1) mm += __shfl_xor(mm, m, 64);
        float mn = sqrtf(mm);
        float mc = fminf(fmaxf(mn, 1e-15f), 0.996f);
        float msc = ((mn > 0.996f) ? (0.996f / mn) : 1.f) * artanh_clip(mc) / mc;
#pragma unroll
        for (int nf = 0; nf < 4; ++nf) outv[nf] = mv[nf] * msc;
    }
}

// fused layer-1 GEMM + bucket histogram.
// GEMM: stage raw bf16(x) (no reduction on critical path); expmap0/proj scale
// f folded into the epilogue via linearity W@(f·x) = f·(W@x).
__global__ __launch_bounds__(256) void k_gemm1_hist(
        const float* __restrict__ x, const ushort_t* __restrict__ Bpk,
        const float* __restrict__ hb, const float* __restrict__ hbn_p,
        ushort_t* __restrict__ htout, int n, int gBlocks,
        const int* __restrict__ dst, int* __restrict__ gBktCnt, int e, int nb) {
    constexpr int RB = 256;
    __shared__ __align__(16) unsigned char As[64 * RB];
    __shared__ float pns[64], fs[64];
    __shared__ int cnt[512];
    int tid = threadIdx.x;
    if ((int)blockIdx.x >= gBlocks) {
        // bucket histogram chunk (LDS pre-aggregated)
        for (int t = tid; t < nb; t += 256) cnt[t] = 0;
        __syncthreads();
        int start = ((int)blockIdx.x - gBlocks) * CHUNK, end = min(e, start + CHUNK);
        for (int i = start + tid; i < end; i += 256)
            atomicAdd(&cnt[dst[i] >> 8], 1);
        __syncthreads();
        for (int t = tid; t < nb; t += 256)
            if (cnt[t]) atomicAdd(&gBktCnt[t], cnt[t]);
        return;
    }
    int wv = tid >> 6, lane = tid & 63;
    int grp = lane >> 4, l = lane & 15;
    int rowBase = blockIdx.x * 64;
    // stage: 4 rows/wave in flight; lane covers 8 elements (32B load, 16B store)
#pragma unroll
    for (int it = 0; it < 4; ++it) {
        int row = wv * 16 + it * 4 + grp, rg = rowBase + row;
        float4 va = make_float4(0.f, 0.f, 0.f, 0.f), vb = va;
        if (rg < n) {
            const float4* xr = (const float4*)(x + (size_t)rg * NFEAT + l * 8);
            va = xr[0]; vb = xr[1];
        }
        uint4 pk;
        pk.x = pack2(va.x, va.y); pk.y = pack2(va.z, va.w);
        pk.z = pack2(vb.x, vb.y); pk.w = pack2(vb.z, vb.w);
        unsigned byte = (unsigned)(row * RB + l * 16) ^ ((row & 7) << 4);
        *(uint4*)(As + byte) = pk;
        float ss = va.x * va.x + va.y * va.y + va.z * va.z + va.w * va.w +
                   vb.x * vb.x + vb.y * vb.y + vb.z * vb.z + vb.w * vb.w;
#pragma unroll
        for (int m = 1; m < 16; m <<= 1) ss += __shfl_xor(ss, m, 64);
        if (l == 0) {
            float nr = fmaxf(sqrtf(ss), 1e-15f);
            float th = fast_tanh(nr);
            float f = th / nr;
            float pn = fmaxf(th, 1e-15f);
            if (th > 0.996f) { f = 0.996f / nr; pn = 0.996f; }
            pns[row] = pn; fs[row] = f;
        }
    }
    int hi = lane >> 4, c = lane & 15;
    short8 bf[4][4];
#pragma unroll
    for (int ks = 0; ks < 4; ++ks)
#pragma unroll
        for (int nf = 0; nf < 4; ++nf)
            bf[ks][nf] = *(const short8*)(Bpk + (((size_t)(ks * 4 + hi) * 4 + nf) * 16 + c) * 8);
    floatx4 acc[4];
#pragma unroll
    for (int nf = 0; nf < 4; ++nf)
#pragma unroll
        for (int r = 0; r < 4; ++r) acc[nf][r] = 0.f;
    int arow = wv * 16 + c;
#pragma unroll
    for (int ks = 0; ks < 4; ++ks) {
        unsigned byte = (unsigned)(arow * RB + ks * 64 + hi * 16) ^ ((arow & 7) << 4);
        short8 af = *(const short8*)(As + byte);
#pragma unroll
        for (int nf = 0; nf < 4; ++nf)
            acc[nf] = __builtin_amdgcn_mfma_f32_16x16x32_bf16(af, bf[ks][nf], acc[nf], 0, 0, 0);
    }
    float hbn = hbn_p[0];
#pragma unroll
    for (int r = 0; r < 4; ++r) {
        int row = wv * 16 + hi * 4 + r, rg = rowBase + row;
        float f = fs[row];
        float vin[4], outv[4];
#pragma unroll
        for (int nf = 0; nf < 4; ++nf) vin[nf] = acc[nf][r] * f;
        epi_vals(vin, pns[row], hbn, hb, c, outv);
        if (rg < n) {
#pragma unroll
            for (int nf = 0; nf < 4; ++nf)
                htout[(size_t)rg * 64 + nf * 16 + c] = f2bf(outv[nf]);
        }
    }
}

// layers 2/3 GEMM (8B/lane staging)
__global__ __launch_bounds__(256) void k_gemm64(
        const ushort_t* __restrict__ h, const float* __restrict__ nrm_in,
        const ushort_t* __restrict__ Bpk, const float* __restrict__ hb,
        const float* __restrict__ hbn_p, ushort_t* __restrict__ htout, int n) {
    constexpr int RB = 128;
    __shared__ __align__(16) unsigned char As[64 * RB];
    int tid = threadIdx.x, wv = tid >> 6, lane = tid & 63;
    int grp = lane >> 4, l = lane & 15;
    int rowBase = blockIdx.x * 64;
#pragma unroll
    for (int it = 0; it < 4; ++it) {
        int row = wv * 16 + it * 4 + grp, rg = rowBase + row;
        uint2 pk = make_uint2(0u, 0u);
        if (rg < n) pk = *(const uint2*)(h + (size_t)rg * 64 + l * 4);
        unsigned byte = (unsigned)(row * RB + l * 8) ^ ((row & 7) << 4);
        *(uint2*)(As + byte) = pk;
    }
    int hi = lane >> 4, c = lane & 15;
    short8 bf[2][4];
#pragma unroll
    for (int ks = 0; ks < 2; ++ks)
#pragma unroll
        for (int nf = 0; nf < 4; ++nf)
            bf[ks][nf] = *(const short8*)(Bpk + (((size_t)(ks * 4 + hi) * 4 + nf) * 16 + c) * 8);
    floatx4 acc[4];
#pragma unroll
    for (int nf = 0; nf < 4; ++nf)
#pragma unroll
        for (int r = 0; r < 4; ++r) acc[nf][r] = 0.f;
    int arow = wv * 16 + c;
#pragma unroll
    for (int ks = 0; ks < 2; ++ks) {
        unsigned byte = (unsigned)(arow * RB + ks * 64 + hi * 16) ^ ((arow & 7) << 4);
        short8 af = *(const short8*)(As + byte);
#pragma unroll
        for (int nf = 0; nf < 4; ++nf)
            acc[nf] = __builtin_amdgcn_mfma_f32_16x16x32_bf16(af, bf[ks][nf], acc[nf], 0, 0, 0);
    }
    float hbn = hbn_p[0];
#pragma unroll
    for (int r = 0; r < 4; ++r) {
        int row = wv * 16 + hi * 4 + r, rg = rowBase + row;
        float pn = (rg < n) ? nrm_in[rg] : 1e-15f;
        float vin[4], outv[4];
#pragma unroll
        for (int nf = 0; nf < 4; ++nf) vin[nf] = acc[nf][r];
        epi_vals(vin, pn, hbn, hb, c, outv);
        if (rg < n) {
#pragma unroll
            for (int nf = 0; nf < 4; ++nf)
                htout[(size_t)rg * 64 + nf * 16 + c] = f2bf(outv[nf]);
        }
    }
}

// CSR aggregation + HypAct. 16 lanes per node; lane owns 4 features (8B);
// 4-deep edge ILP.
template <bool TANGENT_OUT>
__global__ __launch_bounds__(256) void k_agg_act(
        const ushort_t* __restrict__ ht, const int* __restrict__ off,
        const unsigned* __restrict__ pe, ushort_t* __restrict__ hout,
        float* __restrict__ nrm_out, int n) {
    int tid = threadIdx.x;
    int grp = tid >> 4, l = tid & 15;
    int node = blockIdx.x * 16 + grp;
    if (node >= n) return;
    int beg = off[node], end = off[node + 1];
    const char* hb8 = (const char*)ht + l * 8;
    float a0[4] = {0.f, 0.f, 0.f, 0.f};
    float a1[4] = {0.f, 0.f, 0.f, 0.f};
    float a2[4] = {0.f, 0.f, 0.f, 0.f};
    float a3[4] = {0.f, 0.f, 0.f, 0.f};
    int e = beg;
    for (; e + 3 < end; e += 4) {
        unsigned p0 = pe[e], p1 = pe[e + 1], p2 = pe[e + 2], p3 = pe[e + 3];
        uint2 r0 = *(const uint2*)(hb8 + ((size_t)(p0 >> 15) << 7));
        uint2 r1 = *(const uint2*)(hb8 + ((size_t)(p1 >> 15) << 7));
        uint2 r2 = *(const uint2*)(hb8 + ((size_t)(p2 >> 15) << 7));
        uint2 r3 = *(const uint2*)(hb8 + ((size_t)(p3 >> 15) << 7));
        float w0 = pe_adj(p0), w1 = pe_adj(p1), w2 = pe_adj(p2), w3 = pe_adj(p3);
        a0[0] = fmaf(w0, __uint_as_float(r0.x << 16), a0[0]);
        a0[1] = fmaf(w0, __uint_as_float(r0.x & 0xffff0000u), a0[1]);
        a0[2] = fmaf(w0, __uint_as_float(r0.y << 16), a0[2]);
        a0[3] = fmaf(w0, __uint_as_float(r0.y & 0xffff0000u), a0[3]);
        a1[0] = fmaf(w1, __uint_as_float(r1.x << 16), a1[0]);
        a1[1] = fmaf(w1, __uint_as_float(r1.x & 0xffff0000u), a1[1]);
        a1[2] = fmaf(w1, __uint_as_float(r1.y << 16), a1[2]);
        a1[3] = fmaf(w1, __uint_as_float(r1.y & 0xffff0000u), a1[3]);
        a2[0] = fmaf(w2, __uint_as_float(r2.x << 16), a2[0]);
        a2[1] = fmaf(w2, __uint_as_float(r2.x & 0xffff0000u), a2[1]);
        a2[2] = fmaf(w2, __uint_as_float(r2.y << 16), a2[2]);
        a2[3] = fmaf(w2, __uint_as_float(r2.y & 0xffff0000u), a2[3]);
        a3[0] = fmaf(w3, __uint_as_float(r3.x << 16), a3[0]);
        a3[1] = fmaf(w3, __uint_as_float(r3.x & 0xffff0000u), a3[1]);
        a3[2] = fmaf(w3, __uint_as_float(r3.y << 16), a3[2]);
        a3[3] = fmaf(w3, __uint_as_float(r3.y & 0xffff0000u), a3[3]);
    }
    for (; e < end; ++e) {
        unsigned p = pe[e];
        uint2 r = *(const uint2*)(hb8 + ((size_t)(p >> 15) << 7));
        float w = pe_adj(p);
        a0[0] = fmaf(w, __uint_as_float(r.x << 16), a0[0]);
        a0[1] = fmaf(w, __uint_as_float(r.x & 0xffff0000u), a0[1]);
        a0[2] = fmaf(w, __uint_as_float(r.y << 16), a0[2]);
        a0[3] = fmaf(w, __uint_as_float(r.y & 0xffff0000u), a0[3]);
    }
    float f0 = (a0[0] + a1[0]) + (a2[0] + a3[0]);
    float f1 = (a0[1] + a1[1]) + (a2[1] + a3[1]);
    float f2 = (a0[2] + a1[2]) + (a2[2] + a3[2]);
    float f3 = (a0[3] + a1[3]) + (a2[3] + a3[3]);
    float ss = f0 * f0 + f1 * f1 + f2 * f2 + f3 * f3;
#pragma unroll
    for (int m = 1; m < 16; m <<= 1) ss += __shfl_xor(ss, m, 64);
    float un = fmaxf(sqrtf(ss), 1e-15f);
    float thu = fast_tanh(un);
    float pf = thu / un, pn = thu;
    if (thu > 0.996f) { pf = 0.996f / un; pn = 0.996f; }
    float pnc = fmaxf(pn, 1e-15f);
    float ls = artanh_clip(pnc) / pnc * pf;
    float t0 = fmaxf(ls * f0, 0.f), t1 = fmaxf(ls * f1, 0.f);
    float t2 = fmaxf(ls * f2, 0.f), t3 = fmaxf(ls * f3, 0.f);
    float ss2 = t0 * t0 + t1 * t1 + t2 * t2 + t3 * t3;
#pragma unroll
    for (int m = 1; m < 16; m <<= 1) ss2 += __shfl_xor(ss2, m, 64);
    float tn = fmaxf(sqrtf(ss2), 1e-15f);
    uint2 ov;
    if (TANGENT_OUT) {
        float sc = (tn > ATH996) ? (ATH996 / tn) : 1.f;
        ov = make_uint2(pack2(t0 * sc, t1 * sc), pack2(t2 * sc, t3 * sc));
    } else {
        float tht = fast_tanh(tn);
        float rf = tht / tn, rn = tht;
        if (tht > 0.996f) { rf = 0.996f / tn; rn = 0.996f; }
        ov = make_uint2(pack2(rf * t0, rf * t1), pack2(rf * t2, rf * t3));
        if (l == 0) nrm_out[node] = fmaxf(rn, 1e-15f);
    }
    *(uint2*)((char*)hout + (size_t)node * 128 + l * 8) = ov;
}

// MFMA head: z = relu(t@W4.T+b4); out = log_softmax(z@W5.T+b5)
__global__ __launch_bounds__(256) void k_head(
        const ushort_t* __restrict__ t_in, const ushort_t* __restrict__ Bpk4,
        const float* __restrict__ b4, const ushort_t* __restrict__ Bpk5,
        const float* __restrict__ b5, float* __restrict__ out, int n) {
    constexpr int RB = 128;
    __shared__ __align__(16) unsigned char As[64 * RB];
    __shared__ __align__(16) unsigned char Zs[4][16 * 80];  // 80B rows: 2-way max
    int tid = threadIdx.x, wv = tid >> 6, lane = tid & 63;
    int grp = lane >> 4, l = lane & 15;
    int rowBase = blockIdx.x * 64;
#pragma unroll
    for (int it = 0; it < 4; ++it) {
        int row = wv * 16 + it * 4 + grp, rg = rowBase + row;
        uint2 pk = make_uint2(0u, 0u);
        if (rg < n) pk = *(const uint2*)(t_in + (size_t)rg * 64 + l * 4);
        unsigned byte = (unsigned)(row * RB + l * 8) ^ ((row & 7) << 4);
        *(uint2*)(As + byte) = pk;
    }
    int hi = lane >> 4, c = lane & 15;
    short8 bf4[2][2];
#pragma unroll
    for (int ks = 0; ks < 2; ++ks)
#pragma unroll
        for (int nf = 0; nf < 2; ++nf)
            bf4[ks][nf] = *(const short8*)(Bpk4 + (((size_t)(ks * 4 + hi) * 2 + nf) * 16 + c) * 8);
    floatx4 acc[2];
#pragma unroll
    for (int nf = 0; nf < 2; ++nf)
#pragma unroll
        for (int r = 0; r < 4; ++r) acc[nf][r] = 0.f;
    int arow = wv * 16 + c;
#pragma unroll
    for (int ks = 0; ks < 2; ++ks) {
        unsigned byte = (unsigned)(arow * RB + ks * 64 + hi * 16) ^ ((arow & 7) << 4);
        short8 af = *(const short8*)(As + byte);
#pragma unroll
        for (int nf = 0; nf < 2; ++nf)
            acc[nf] = __builtin_amdgcn_mfma_f32_16x16x32_bf16(af, bf4[ks][nf], acc[nf], 0, 0, 0);
    }
    float bb0 = b4[c], bb1 = b4[16 + c];
#pragma unroll
    for (int r = 0; r < 4; ++r) {
        int zr = hi * 4 + r;
        *(ushort_t*)(Zs[wv] + zr * 80 + c * 2) = f2bf(fmaxf(acc[0][r] + bb0, 0.f));
        *(ushort_t*)(Zs[wv] + zr * 80 + (16 + c) * 2) = f2bf(fmaxf(acc[1][r] + bb1, 0.f));
    }
    short8 bf5 = *(const short8*)(Bpk5 + ((size_t)(hi * 16 + c)) * 8);
    short8 zf = *(const short8*)(Zs[wv] + c * 80 + hi * 16);
    floatx4 acc5;
#pragma unroll
    for (int r = 0; r < 4; ++r) acc5[r] = 0.f;
    acc5 = __builtin_amdgcn_mfma_f32_16x16x32_bf16(zf, bf5, acc5, 0, 0, 0);
    float b5v = b5[c];
#pragma unroll
    for (int r = 0; r < 4; ++r) {
        float y = acc5[r] + b5v;
        float mx = y;
#pragma unroll
        for (int mk = 1; mk < 16; mk <<= 1) mx = fmaxf(mx, __shfl_xor(mx, mk, 64));
        float sm = __expf(y - mx);
#pragma unroll
        for (int mk = 1; mk < 16; mk <<= 1) sm += __shfl_xor(sm, mk, 64);
        int rg = rowBase + wv * 16 + hi * 4 + r;
        if (rg < n) out[(size_t)rg * 16 + c] = y - mx - __logf(sm);
    }
}

extern "C" void kernel_launch(void* const* d_in, const int* in_sizes, int n_in,
                              void* d_out, int out_size, void* d_ws, size_t ws_size,
                              hipStream_t stream) {
    const float* x   = (const float*)d_in[0];
    const int*   src = (const int*)d_in[1];
    const int*   dst = (const int*)d_in[2];
    const float* adj = (const float*)d_in[3];
    const float* W1  = (const float*)d_in[4];  const float* b1 = (const float*)d_in[5];
    const float* W2  = (const float*)d_in[6];  const float* b2 = (const float*)d_in[7];
    const float* W3  = (const float*)d_in[8];  const float* b3 = (const float*)d_in[9];
    const float* W4  = (const float*)d_in[10]; const float* b4 = (const float*)d_in[11];
    const float* W5  = (const float*)d_in[12]; const float* b5 = (const float*)d_in[13];
    float* out = (float*)d_out;

    const int N = in_sizes[0] / NFEAT;
    const int E = in_sizes[1];
    const int NB = (N + 255) >> 8;   // 256-node buckets (<= 512)

    // ws layout, every region 256B-aligned
    char* w = (char*)d_ws;
    auto alloc = [&](size_t bytes) {
        char* p = w; w += (bytes + 255) & ~(size_t)255; return p;
    };
    int* off      = (int*)alloc((size_t)(N + 1) * 4);
    int* gBktCnt  = (int*)alloc((size_t)NB * 4);
    int* gBktBase = (int*)alloc((size_t)(NB + 1) * 4);
    int* gCur     = (int*)alloc((size_t)NB * 4);
    u64* gStage   = (u64*)alloc((size_t)E * 8);
    unsigned* pe  = (unsigned*)alloc((size_t)E * 4);
    ushort_t* B   = (ushort_t*)alloc((size_t)N * 64 * 2);
    ushort_t* D   = (ushort_t*)alloc((size_t)N * 64 * 2);
    float* nrm    = (float*)alloc((size_t)N * 4);
    float* hbs    = (float*)alloc(192 * 4);
    float* hbns   = (float*)alloc(4 * 4);
    ushort_t* Bpk1 = (ushort_t*)alloc(8192 * 2);
    ushort_t* Bpk2 = (ushort_t*)alloc(4096 * 2);
    ushort_t* Bpk3 = (ushort_t*)alloc(4096 * 2);
    ushort_t* Bpk4 = (ushort_t*)alloc(2048 * 2);
    ushort_t* Bpk5 = (ushort_t*)alloc(512 * 2);

    dim3 blk(256);
    int aggBlocks  = (N + 15) / 16;
    int gemmBlocks = (N + 63) / 64;
    int sortBlocks = (E + CHUNK - 1) / CHUNK;

    // prep: weight packs + biases + bucket-count zeroing
    k_prep<<<76, blk, 0, stream>>>(W1, W2, W3, W4, W5, b1, b2, b3,
                                   Bpk1, Bpk2, Bpk3, Bpk4, Bpk5, hbs, hbns,
                                   gBktCnt, NB);

    // fused: layer-1 GEMM || bucket histogram (independent)
    k_gemm1_hist<<<gemmBlocks + sortBlocks, blk, 0, stream>>>(
        x, Bpk1, hbs, hbns, B, N, gemmBlocks, dst, gBktCnt, E, NB);

    // bucketed CSR build
    k_bscan<<<1, blk, 0, stream>>>(gBktCnt, gBktBase, gCur, off, NB, N, E);
    k_bscatter<<<sortBlocks, blk, 0, stream>>>(dst, src, adj, gCur, gStage, E, NB);
    k_bfinal<<<NB, blk, 0, stream>>>(gStage, gBktBase, off, pe, N);

    // layer 1 aggregation (+act)
    k_agg_act<false><<<aggBlocks, blk, 0, stream>>>(B, off, pe, D, nrm, N);
    // layer 2
    k_gemm64<<<gemmBlocks, blk, 0, stream>>>(D, nrm, Bpk2, hbs + 64, hbns + 1, B, N);
    k_agg_act<false><<<aggBlocks, blk, 0, stream>>>(B, off, pe, D, nrm, N);
    // layer 3
    k_gemm64<<<gemmBlocks, blk, 0, stream>>>(D, nrm, Bpk3, hbs + 128, hbns + 2, B, N);
    k_agg_act<true><<<aggBlocks, blk, 0, stream>>>(B, off, pe, D, nullptr, N);

    // head (MFMA)
    k_head<<<gemmBlocks, blk, 0, stream>>>(D, Bpk4, b4, Bpk5, b5, out, N);
}